// Round 18
// baseline (3943.162 us; speedup 1.0000x reference)
//
#include <hip/hip_runtime.h>

#define NN   100000
#define DD   64
#define EE   3200000
#define GG   128
#define FF   1344
#define KK   60
#define RK   50
#define HIDN 32
#define NCL  696
#define BSPLIT 96
#define GSL  64
#define PN   40

// OMEGA xor-fold VERIFIED r3. JACOBI: 3 sweeps VERIFIED r10-r17 (absmax 48); 2 sweeps FAILED r15.
// split-bf16 MFMA fwd/bwd VERIFIED r8/r9. hi/lo precompute r10+. Qj fused into k_fwd r17.
// LESSON r10: wide part-reduce stays multi-block. LESSON r16: slab-atomic bwd net-negative.
// r18: granular TT — per-tensor transposed copies, as many as ws fits (nTT in [0,5]);
//      k_bwd unified with per-t-block branch (TT bulk copy vs r13 scatter; bit-identical LDS).

typedef short short8 __attribute__((ext_vector_type(8)));
typedef float f32x4 __attribute__((ext_vector_type(4)));

__device__ __forceinline__ unsigned short f2bf(float x){
  unsigned u = __float_as_uint(x);
  unsigned r = u + 0x7fffu + ((u>>16)&1u);
  return (unsigned short)(r>>16);
}
__device__ __forceinline__ float bf2f(unsigned short h){
  return __uint_as_float(((unsigned)h)<<16);
}

// ---------------- threefry + erfinv ----------------
__device__ __forceinline__ unsigned rotl32(unsigned x, unsigned r){ return (x<<r)|(x>>(32u-r)); }

__device__ __forceinline__ void threefry(unsigned& x0, unsigned& x1){
  const unsigned ks0 = 0u, ks1 = 42u, ks2 = 0x1BD11BDAu ^ 0u ^ 42u;
  unsigned ks[3] = {ks0, ks1, ks2};
  const unsigned rotA[4] = {13u,15u,26u,6u};
  const unsigned rotB[4] = {17u,29u,16u,24u};
  x0 += ks0; x1 += ks1;
  #pragma unroll
  for (int i = 0; i < 5; ++i){
    #pragma unroll
    for (int j = 0; j < 4; ++j){
      unsigned r = (i & 1) ? rotB[j] : rotA[j];
      x0 += x1; x1 = rotl32(x1, r); x1 ^= x0;
    }
    x0 += ks[(i+1)%3]; x1 += ks[(i+2)%3] + (unsigned)(i+1);
  }
}

__device__ __forceinline__ float bits_to_normal(unsigned bits){
  unsigned mant = bits >> 9;
  float f; { unsigned fb = 0x3f800000u | mant; f = __uint_as_float(fb); }
  f -= 1.0f;
  const float lo = -0.99999994f;
  float u = fmaf(f, 2.0f, lo);
  u = fmaxf(lo, u);
  float w = -log1pf(-u*u);
  float p;
  if (w < 5.0f){
    w -= 2.5f;
    p = 2.81022636e-08f;
    p = fmaf(p, w, 3.43273939e-07f);
    p = fmaf(p, w, -3.5233877e-06f);
    p = fmaf(p, w, -4.39150654e-06f);
    p = fmaf(p, w, 0.00021858087f);
    p = fmaf(p, w, -0.00125372503f);
    p = fmaf(p, w, -0.00417768164f);
    p = fmaf(p, w, 0.246640727f);
    p = fmaf(p, w, 1.50140941f);
  } else {
    w = sqrtf(w) - 3.0f;
    p = -0.000200214257f;
    p = fmaf(p, w, 0.000100950558f);
    p = fmaf(p, w, 0.00134934322f);
    p = fmaf(p, w, -0.00367342844f);
    p = fmaf(p, w, 0.00573950773f);
    p = fmaf(p, w, -0.0076224613f);
    p = fmaf(p, w, 0.00943887047f);
    p = fmaf(p, w, 1.00167406f);
    p = fmaf(p, w, 2.83297682f);
  }
  return 1.41421356f * (p * u);
}

__global__ void k_omega(float* __restrict__ om){
  int i = blockIdx.x*blockDim.x + threadIdx.x;
  if (i >= FF*KK) return;
  unsigned x0 = 0u, x1 = (unsigned)i;
  threefry(x0, x1);
  om[i] = bits_to_normal(x0 ^ x1);
}

// ---------------- CSR build ----------------
__global__ void k_count(const int* __restrict__ rows, int* __restrict__ cnt){
  int e = blockIdx.x*blockDim.x + threadIdx.x;
  if (e < EE) atomicAdd(&cnt[rows[e]], 1);
}

__global__ __launch_bounds__(1024) void k_scan1(const int* __restrict__ cnt,
    int* __restrict__ incl, int* __restrict__ bsums){
  __shared__ int buf[1024];
  int i = blockIdx.x*1024 + threadIdx.x;
  int v = (i < NN) ? cnt[i] : 0;
  buf[threadIdx.x] = v; __syncthreads();
  for (int ofs = 1; ofs < 1024; ofs <<= 1){
    int add = (threadIdx.x >= (unsigned)ofs) ? buf[threadIdx.x - ofs] : 0;
    __syncthreads();
    buf[threadIdx.x] += add;
    __syncthreads();
  }
  if (i < NN) incl[i] = buf[threadIdx.x];
  if (threadIdx.x == 1023) bsums[blockIdx.x] = buf[1023];
}

__global__ void k_scan2(int* __restrict__ bsums, int nb){
  if (threadIdx.x == 0){
    int run = 0;
    for (int i = 0; i < nb; ++i){ int v = bsums[i]; bsums[i] = run; run += v; }
  }
}

__global__ void k_scan3(const int* __restrict__ cnt, const int* __restrict__ bsums,
                        int* __restrict__ rowptr){
  int i = blockIdx.x*blockDim.x + threadIdx.x;
  if (i >= NN) return;
  int incl = rowptr[i];
  int ex = incl - cnt[i] + bsums[i >> 10];
  rowptr[i] = ex;
  if (i == NN-1) rowptr[NN] = ex + cnt[i];
}

__global__ void k_scatter(const int* __restrict__ rows, const int* __restrict__ cols,
                          const int* __restrict__ rowptr, int* __restrict__ tmpc,
                          int* __restrict__ csr){
  int e = blockIdx.x*blockDim.x + threadIdx.x;
  if (e >= EE) return;
  int r = rows[e];
  int p = atomicAdd(&tmpc[r], 1);
  csr[rowptr[r] + p] = cols[e];
}

__global__ void k_degr(const int* __restrict__ cnt, float* __restrict__ r1, float* __restrict__ r2){
  int i = blockIdx.x*blockDim.x + threadIdx.x;
  if (i >= NN) return;
  int d = cnt[i];
  float fd = (float)d;
  r1[i] = (d > 0) ? 1.0f/fd : 1.0f;
  r2[i] = 1.0f/(fd + 1e-5f);
}

// ---------------- x -> hi/lo ----------------
__global__ void k_xcvt(const float* __restrict__ x,
                       unsigned short* __restrict__ xh, unsigned short* __restrict__ xl){
  int gid = blockIdx.x*blockDim.x + threadIdx.x;
  if (gid >= NN*64) return;
  float v = x[gid];
  unsigned short h = f2bf(v);
  xh[gid] = h;
  xl[gid] = f2bf(v - bf2f(h));
}

// ---------------- propagation ----------------
__global__ __launch_bounds__(256) void k_hop1(const float* __restrict__ x,
    const int* __restrict__ rp, const int* __restrict__ cc, float* __restrict__ ax,
    unsigned short* __restrict__ axh, unsigned short* __restrict__ axl){
  int n = blockIdx.x*4 + (threadIdx.x >> 6);
  int lane = threadIdx.x & 63;
  if (n >= NN) return;
  int s = rp[n], e = rp[n+1];
  float acc = 0.f;
  int idx = s;
  for (; idx + 8 <= e; idx += 8){
    int c0 = cc[idx], c1 = cc[idx+1], c2 = cc[idx+2], c3 = cc[idx+3];
    int c4 = cc[idx+4], c5 = cc[idx+5], c6 = cc[idx+6], c7 = cc[idx+7];
    float v0 = x[(size_t)c0*64 + lane];
    float v1 = x[(size_t)c1*64 + lane];
    float v2 = x[(size_t)c2*64 + lane];
    float v3 = x[(size_t)c3*64 + lane];
    float v4 = x[(size_t)c4*64 + lane];
    float v5 = x[(size_t)c5*64 + lane];
    float v6 = x[(size_t)c6*64 + lane];
    float v7 = x[(size_t)c7*64 + lane];
    acc += ((v0 + v1) + (v2 + v3)) + ((v4 + v5) + (v6 + v7));
  }
  for (; idx < e; ++idx) acc += x[(size_t)cc[idx]*64 + lane];
  size_t o = (size_t)n*64 + lane;
  ax[o] = acc;
  unsigned short h = f2bf(acc);
  axh[o] = h;
  axl[o] = f2bf(acc - bf2f(h));
}

__global__ __launch_bounds__(256) void k_hop2(const int* __restrict__ rp, const int* __restrict__ cc,
    const float* __restrict__ ax, const float* __restrict__ r1, const float* __restrict__ r2,
    unsigned short* __restrict__ s0h, unsigned short* __restrict__ s0l,
    unsigned short* __restrict__ s1h, unsigned short* __restrict__ s1l,
    unsigned short* __restrict__ s3h, unsigned short* __restrict__ s3l){
  int n = blockIdx.x*4 + (threadIdx.x >> 6);
  int lane = threadIdx.x & 63;
  if (n >= NN) return;
  int s = rp[n], e = rp[n+1];
  float v_s0 = 0.f, v_s1 = 0.f, v_s3 = 0.f;
  int idx = s;
  for (; idx + 8 <= e; idx += 8){
    int c0 = cc[idx], c1 = cc[idx+1], c2 = cc[idx+2], c3 = cc[idx+3];
    int c4 = cc[idx+4], c5 = cc[idx+5], c6 = cc[idx+6], c7 = cc[idx+7];
    float v0 = ax[(size_t)c0*64 + lane], a0 = r1[c0], b0 = r2[c0];
    float v1 = ax[(size_t)c1*64 + lane], a1 = r1[c1], b1 = r2[c1];
    float v2 = ax[(size_t)c2*64 + lane], a2 = r1[c2], b2 = r2[c2];
    float v3 = ax[(size_t)c3*64 + lane], a3 = r1[c3], b3 = r2[c3];
    float v4 = ax[(size_t)c4*64 + lane], a4 = r1[c4], b4 = r2[c4];
    float v5 = ax[(size_t)c5*64 + lane], a5 = r1[c5], b5 = r2[c5];
    float v6 = ax[(size_t)c6*64 + lane], a6 = r1[c6], b6 = r2[c6];
    float v7 = ax[(size_t)c7*64 + lane], a7 = r1[c7], b7 = r2[c7];
    v_s0 += ((v0 + v1) + (v2 + v3)) + ((v4 + v5) + (v6 + v7));
    v_s1 = fmaf(v0,a0,fmaf(v1,a1,fmaf(v2,a2,fmaf(v3,a3,v_s1))));
    v_s1 = fmaf(v4,a4,fmaf(v5,a5,fmaf(v6,a6,fmaf(v7,a7,v_s1))));
    v_s3 = fmaf(v0,b0,fmaf(v1,b1,fmaf(v2,b2,fmaf(v3,b3,v_s3))));
    v_s3 = fmaf(v4,b4,fmaf(v5,b5,fmaf(v6,b6,fmaf(v7,b7,v_s3))));
  }
  for (; idx < e; ++idx){
    int c = cc[idx];
    float v = ax[(size_t)c*64 + lane];
    v_s0 += v;
    v_s1 = fmaf(v, r1[c], v_s1);
    v_s3 = fmaf(v, r2[c], v_s3);
  }
  size_t o = (size_t)n*64 + lane;
  unsigned short h0 = f2bf(v_s0);
  s0h[o] = h0; s0l[o] = f2bf(v_s0 - bf2f(h0));
  unsigned short h1 = f2bf(v_s1);
  s1h[o] = h1; s1l[o] = f2bf(v_s1 - bf2f(h1));
  unsigned short h3 = f2bf(v_s3);
  s3h[o] = h3; s3l[o] = f2bf(v_s3 - bf2f(h3));
}

// ---------------- one-time: TT[rel*64+f][n] = T_{tstart+rel} hi/lo transposed ----------------
__global__ __launch_bounds__(256) void k_tcvt(
    const unsigned short* __restrict__ xh, const unsigned short* __restrict__ xl,
    const unsigned short* __restrict__ axh, const unsigned short* __restrict__ axl,
    const unsigned short* __restrict__ s0h, const unsigned short* __restrict__ s0l,
    const unsigned short* __restrict__ s1h, const unsigned short* __restrict__ s1l,
    const unsigned short* __restrict__ s3h, const unsigned short* __restrict__ s3l,
    int tstart,
    unsigned short* __restrict__ TTh, unsigned short* __restrict__ TTl){
  __shared__ unsigned short Sh[64][72];
  __shared__ unsigned short Sl[64][72];
  int rel = blockIdx.y;
  int t = tstart + rel;
  const unsigned short* inh = (t==0)?xh:(t==1)?axh:(t==2)?s0h:(t==3)?s1h:s3h;
  const unsigned short* inl = (t==0)?xl:(t==1)?axl:(t==2)?s0l:(t==3)?s1l:s3l;
  int n0 = blockIdx.x*64;
  int tid = threadIdx.x;
  #pragma unroll
  for (int l = 0; l < 2; ++l){
    int li = tid + l*256;
    int n = li >> 3, f8 = (li & 7)*8;
    int gn = n0 + n;
    uint4 hv = make_uint4(0,0,0,0), lv = make_uint4(0,0,0,0);
    if (gn < NN){
      hv = *(const uint4*)(inh + (size_t)gn*64 + f8);
      lv = *(const uint4*)(inl + (size_t)gn*64 + f8);
    }
    *(uint4*)(&Sh[n][f8]) = hv;
    *(uint4*)(&Sl[n][f8]) = lv;
  }
  __syncthreads();
  #pragma unroll
  for (int l = 0; l < 2; ++l){
    int li = tid + l*256;
    int f = li >> 3, ch = (li & 7)*8;
    int gn0 = n0 + ch;
    if (gn0 + 8 <= NN){
      unsigned short hv[8], lv2[8];
      #pragma unroll
      for (int i = 0; i < 8; ++i){ hv[i] = Sh[ch+i][f]; lv2[i] = Sl[ch+i][f]; }
      *(uint4*)(TTh + (size_t)(rel*64+f)*NN + gn0) = *(uint4*)hv;
      *(uint4*)(TTl + (size_t)(rel*64+f)*NN + gn0) = *(uint4*)lv2;
    }
  }
}

// ---------------- Beff build ----------------
__global__ void k_beff(const float* __restrict__ B,
                       unsigned short* __restrict__ Beh, unsigned short* __restrict__ Bel){
  int gid = blockIdx.x*blockDim.x + threadIdx.x;
  if (gid >= 20*4096) return;
  int p = gid >> 12;
  int rem = gid & 4095;
  int c = rem >> 6, r = rem & 63;
  int t = p >> 2, j = p & 3;
  float val = 0.f;
  if (c < KK){
    if (t == 0)      val = (j == 0) ? B[(0*64 + r)*60 + c] : 0.f;
    else if (t == 1) val = B[((1+j)*64 + r)*60 + c];
    else if (t == 2) val = B[((5+j)*64 + r)*60 + c] + 1.5e-6f*B[((13+j)*64 + r)*60 + c];
    else if (t == 3) val = B[((9+j)*64 + r)*60 + c] + 0.85f  *B[((13+j)*64 + r)*60 + c];
    else             val = B[((17+j)*64 + r)*60 + c];
  }
  unsigned short h = f2bf(val);
  Beh[gid] = h;
  Bel[gid] = f2bf(val - bf2f(h));
}

__global__ __launch_bounds__(256) void k_beffT(const float* __restrict__ Z,
    const float* __restrict__ Rtot,
    unsigned short* __restrict__ Beh, unsigned short* __restrict__ Bel){
  __shared__ float Br[64][61];
  __shared__ float Rt[60][64];
  int p = blockIdx.x;
  int t2 = p >> 2, j = p & 3;
  int tid = threadIdx.x;
  if (t2 == 0 && j != 0){
    for (int o = tid; o < 4096; o += 256){ Beh[(size_t)p*4096 + o] = 0; Bel[(size_t)p*4096 + o] = 0; }
    return;
  }
  for (int i = tid; i < 3840; i += 256){
    int r = i >> 6, c = i & 63;
    if (c < 60) Rt[r][c] = Rtot[r*60 + c];
  }
  for (int o = tid; o < 64*60; o += 256){
    int r = o / 60, k = o - (o/60)*60;
    float v;
    if (t2 == 0)      v = Z[(0*64 + r)*60 + k];
    else if (t2 == 1) v = Z[((1+j)*64 + r)*60 + k];
    else if (t2 == 2) v = Z[((5+j)*64 + r)*60 + k] + 1.5e-6f*Z[((13+j)*64 + r)*60 + k];
    else if (t2 == 3) v = Z[((9+j)*64 + r)*60 + k] + 0.85f  *Z[((13+j)*64 + r)*60 + k];
    else              v = Z[((17+j)*64 + r)*60 + k];
    Br[r][k] = v;
  }
  __syncthreads();
  for (int o = tid; o < 4096; o += 256){
    int c = o >> 6, r = o & 63;
    float s = 0.f;
    if (c < KK){
      #pragma unroll 10
      for (int kp = 0; kp < 60; ++kp) s = fmaf(Br[r][kp], Rt[kp][c], s);
    }
    unsigned short h = f2bf(s);
    Beh[(size_t)p*4096 + o] = h;
    Bel[(size_t)p*4096 + o] = f2bf(s - bf2f(h));
  }
}

// ---------------- forward: split-bf16 MFMA + fused block-gram + fused Qj emission ----------------
__device__ __forceinline__ void fma44(const float4 a, const float4 b, float (&acc)[4][4]){
  acc[0][0] = fmaf(a.x,b.x,acc[0][0]); acc[0][1] = fmaf(a.x,b.y,acc[0][1]);
  acc[0][2] = fmaf(a.x,b.z,acc[0][2]); acc[0][3] = fmaf(a.x,b.w,acc[0][3]);
  acc[1][0] = fmaf(a.y,b.x,acc[1][0]); acc[1][1] = fmaf(a.y,b.y,acc[1][1]);
  acc[1][2] = fmaf(a.y,b.z,acc[1][2]); acc[1][3] = fmaf(a.y,b.w,acc[1][3]);
  acc[2][0] = fmaf(a.z,b.x,acc[2][0]); acc[2][1] = fmaf(a.z,b.y,acc[2][1]);
  acc[2][2] = fmaf(a.z,b.z,acc[2][2]); acc[2][3] = fmaf(a.z,b.w,acc[2][3]);
  acc[3][0] = fmaf(a.w,b.x,acc[3][0]); acc[3][1] = fmaf(a.w,b.y,acc[3][1]);
  acc[3][2] = fmaf(a.w,b.z,acc[3][2]); acc[3][3] = fmaf(a.w,b.w,acc[3][3]);
}

__global__ __launch_bounds__(256) void k_fwd(
    const unsigned short* __restrict__ xh, const unsigned short* __restrict__ xl,
    const unsigned short* __restrict__ axh, const unsigned short* __restrict__ axl,
    const unsigned short* __restrict__ s0h, const unsigned short* __restrict__ s0l,
    const unsigned short* __restrict__ s1h, const unsigned short* __restrict__ s1l,
    const unsigned short* __restrict__ s3h, const unsigned short* __restrict__ s3l,
    const unsigned short* __restrict__ Beh, const unsigned short* __restrict__ Bel,
    const float* __restrict__ r1, const float* __restrict__ r2,
    float* __restrict__ Y, float* __restrict__ Cpart,
    unsigned short* __restrict__ Qjh, unsigned short* __restrict__ Qjl){
  __shared__ __align__(16) unsigned short AB[4*64*72];
  __shared__ float cS[4][64];
  unsigned short* Ah = AB;
  unsigned short* Al = AB + 64*72;
  unsigned short* Bh = AB + 2*64*72;
  unsigned short* Bl = AB + 3*64*72;
  float* As2 = (float*)AB;
  const unsigned short* Tsh[5] = {xh, axh, s0h, s1h, s3h};
  const unsigned short* Tsl[5] = {xl, axl, s0l, s1l, s3l};
  int n0 = blockIdx.x*64;
  int tid = threadIdx.x;
  int lane = tid & 63, wid = tid >> 6;
  int rowb = (wid & 1)*32, colb = (wid >> 1)*32;
  int l15 = lane & 15, l4 = lane >> 4;

  if (tid < 64){
    int gn = n0 + tid;
    float r1v = 0.f, r2v = 0.f, one = 0.f;
    if (gn < NN){ r1v = r1[gn]; r2v = r2[gn]; one = 1.f; }
    cS[0][tid] = one;
    cS[1][tid] = r1v;
    cS[2][tid] = fmaf(0.85f, r1v, 1.5e-6f*one);
    cS[3][tid] = r2v;
  }

  f32x4 master[2][2] = {};
  int curt = -1;
  for (int plin = 0; plin < 17; ++plin){
    int t  = (plin == 0) ? 0 : (((plin-1) >> 2) + 1);
    int jj = (plin == 0) ? 0 : ((plin-1) & 3);
    int p  = (plin == 0) ? 0 : (plin + 3);
    if (t != curt){
      __syncthreads();
      const unsigned short* Th = Tsh[t];
      const unsigned short* Tl = Tsl[t];
      #pragma unroll
      for (int l = 0; l < 2; ++l){
        int li = tid + l*256;
        int n = li >> 3, f8 = (li & 7)*8;
        int gn = n0 + n;
        uint4 hv = make_uint4(0,0,0,0), lv = make_uint4(0,0,0,0);
        if (gn < NN){
          hv = *(const uint4*)(Th + (size_t)gn*64 + f8);
          lv = *(const uint4*)(Tl + (size_t)gn*64 + f8);
        }
        *(uint4*)(Ah + n*72 + f8) = hv;
        *(uint4*)(Al + n*72 + f8) = lv;
      }
      curt = t;
    }
    __syncthreads();
    #pragma unroll
    for (int l = 0; l < 2; ++l){
      int li = tid + l*256;
      int c = li >> 3, k8 = (li & 7)*8;
      uint4 hv = *(const uint4*)(Beh + (size_t)p*4096 + c*64 + k8);
      uint4 lv = *(const uint4*)(Bel + (size_t)p*4096 + c*64 + k8);
      *(uint4*)(Bh + c*72 + k8) = hv;
      *(uint4*)(Bl + c*72 + k8) = lv;
    }
    __syncthreads();

    float cvv[2][4];
    #pragma unroll
    for (int rg = 0; rg < 2; ++rg)
      #pragma unroll
      for (int r = 0; r < 4; ++r)
        cvv[rg][r] = cS[jj][rowb + rg*16 + l4*4 + r];

    f32x4 part[2][2] = {};
    #pragma unroll
    for (int s = 0; s < 2; ++s){
      int kc = s*32 + l4*8;
      short8 a0h = *(const short8*)(Ah + (rowb      + l15)*72 + kc);
      short8 a1h = *(const short8*)(Ah + (rowb + 16 + l15)*72 + kc);
      short8 a0l = *(const short8*)(Al + (rowb      + l15)*72 + kc);
      short8 a1l = *(const short8*)(Al + (rowb + 16 + l15)*72 + kc);
      #pragma unroll
      for (int cg = 0; cg < 2; ++cg){
        short8 bh = *(const short8*)(Bh + (colb + cg*16 + l15)*72 + kc);
        short8 bl = *(const short8*)(Bl + (colb + cg*16 + l15)*72 + kc);
        part[0][cg] = __builtin_amdgcn_mfma_f32_16x16x32_bf16(a0h, bh, part[0][cg], 0, 0, 0);
        part[0][cg] = __builtin_amdgcn_mfma_f32_16x16x32_bf16(a0h, bl, part[0][cg], 0, 0, 0);
        part[0][cg] = __builtin_amdgcn_mfma_f32_16x16x32_bf16(a0l, bh, part[0][cg], 0, 0, 0);
        part[1][cg] = __builtin_amdgcn_mfma_f32_16x16x32_bf16(a1h, bh, part[1][cg], 0, 0, 0);
        part[1][cg] = __builtin_amdgcn_mfma_f32_16x16x32_bf16(a1h, bl, part[1][cg], 0, 0, 0);
        part[1][cg] = __builtin_amdgcn_mfma_f32_16x16x32_bf16(a1l, bh, part[1][cg], 0, 0, 0);
      }
    }
    #pragma unroll
    for (int rg = 0; rg < 2; ++rg)
      #pragma unroll
      for (int cg = 0; cg < 2; ++cg)
        #pragma unroll
        for (int r = 0; r < 4; ++r)
          master[rg][cg][r] = fmaf(cvv[rg][r], part[rg][cg][r], master[rg][cg][r]);
  }

  // write Y
  #pragma unroll
  for (int rg = 0; rg < 2; ++rg)
    #pragma unroll
    for (int cg = 0; cg < 2; ++cg)
      #pragma unroll
      for (int r = 0; r < 4; ++r){
        int n = rowb + rg*16 + l4*4 + r;
        int c = colb + cg*16 + l15;
        int gn = n0 + n;
        if (gn < NN && c < KK) Y[(size_t)gn*KK + c] = master[rg][cg][r];
      }

  // restage to As2[n][c] for gram + Qj emission
  __syncthreads();
  #pragma unroll
  for (int rg = 0; rg < 2; ++rg)
    #pragma unroll
    for (int cg = 0; cg < 2; ++cg)
      #pragma unroll
      for (int r = 0; r < 4; ++r){
        int n = rowb + rg*16 + l4*4 + r;
        int c = colb + cg*16 + l15;
        As2[n*68 + c] = master[rg][cg][r];
      }
  __syncthreads();
  // fused block-gram
  {
    int tx = tid & 15, ty = tid >> 4;
    float g[4][4] = {};
    #pragma unroll 4
    for (int n = 0; n < 64; ++n){
      float4 a = *(const float4*)(As2 + n*68 + tx*4);
      float4 b = *(const float4*)(As2 + n*68 + ty*4);
      fma44(a, b, g);
    }
    float* slab = Cpart + (size_t)(blockIdx.x & (GSL-1))*3600;
    #pragma unroll
    for (int i = 0; i < 4; ++i){
      int r = tx*4 + i;
      #pragma unroll
      for (int j = 0; j < 4; ++j){
        int c = ty*4 + j;
        if (r < KK && c < KK) atomicAdd(&slab[r*KK + c], g[i][j]);
      }
    }
  }
  // fused Qj emission: Qj[jk][n] = hi/lo of (c_j ∘ Y)^T, j in {0,1,3}
  for (int o = tid; o < 3*64*64; o += 256){
    int nl = o & 63;
    int jk = o >> 6;
    int gn = n0 + nl;
    if (gn >= NN) continue;
    int j = jk >> 6, k = jk & 63;
    float v = (k < KK) ? As2[nl*68 + k] : 0.f;
    float c = (j == 0) ? 1.f : ((j == 1) ? cS[1][nl] : cS[3][nl]);
    float sv = c * v;
    unsigned short h = f2bf(sv);
    Qjh[(size_t)jk*NN + gn] = h;
    Qjl[(size_t)jk*NN + gn] = f2bf(sv - bf2f(h));
  }
}

// ---------------- backward (unified): per-t-block TT bulk copy OR r13 scatter ----------------
// Both paths produce bit-identical LDS content; tstart selects per t-block.
__global__ __launch_bounds__(256) void k_bwd(
    const unsigned short* __restrict__ xh, const unsigned short* __restrict__ xl,
    const unsigned short* __restrict__ axh, const unsigned short* __restrict__ axl,
    const unsigned short* __restrict__ s0h, const unsigned short* __restrict__ s0l,
    const unsigned short* __restrict__ s1h, const unsigned short* __restrict__ s1l,
    const unsigned short* __restrict__ s3h, const unsigned short* __restrict__ s3l,
    const unsigned short* __restrict__ TTh, const unsigned short* __restrict__ TTl,
    int tstart,
    const unsigned short* __restrict__ Qjh, const unsigned short* __restrict__ Qjl,
    float* __restrict__ Ppart){
  int tb = blockIdx.x;
  const unsigned short* Th = (tb==0)?xh:(tb==1)?axh:(tb==2)?s0h:(tb==3)?s1h:s3h;
  const unsigned short* Tl = (tb==0)?xl:(tb==1)?axl:(tb==2)?s0l:(tb==3)?s1l:s3l;
  const bool useT = (tb >= tstart);
  const int rel = tb - tstart;
  const int TT2 = (NN + 31)/32;
  int per = (TT2 + BSPLIT - 1)/BSPLIT;
  int t0 = blockIdx.y * per;
  int t1 = t0 + per; if (t1 > TT2) t1 = TT2;

  __shared__ __align__(16) unsigned short Ah[64*PN];
  __shared__ __align__(16) unsigned short Al[64*PN];
  __shared__ __align__(16) unsigned short Bh3[3*64*PN];
  __shared__ __align__(16) unsigned short Bl3[3*64*PN];

  int tid = threadIdx.x;
  int lane = tid & 63, wid = tid >> 6;
  int rowb = (wid & 1)*32, colb = (wid >> 1)*32;
  int l15 = lane & 15, l4 = lane >> 4;

  f32x4 master[3][2][2] = {};

  for (int tl = t0; tl < t1; ++tl){
    int nb = tl*32;
    __syncthreads();
    if (useT){
      // bulk copy from pre-transposed TT (2 b128 LDS writes/thread)
      int f = tid >> 2, ch = (tid & 3)*8;
      uint4 hv = *(const uint4*)(TTh + (size_t)(rel*64+f)*NN + nb + ch);
      uint4 lv = *(const uint4*)(TTl + (size_t)(rel*64+f)*NN + nb + ch);
      *(uint4*)(Ah + f*PN + ch) = hv;
      *(uint4*)(Al + f*PN + ch) = lv;
    } else {
      // r13 fallback: in-LDS transpose scatter from row-major
      int n = tid >> 3, f8 = (tid & 7)*8;
      int gn = nb + n;
      uint4 hv = make_uint4(0,0,0,0), lv = make_uint4(0,0,0,0);
      if (gn < NN){
        hv = *(const uint4*)(Th + (size_t)gn*64 + f8);
        lv = *(const uint4*)(Tl + (size_t)gn*64 + f8);
      }
      const unsigned short* hp = (const unsigned short*)&hv;
      const unsigned short* lp = (const unsigned short*)&lv;
      #pragma unroll
      for (int i = 0; i < 8; ++i){
        Ah[(f8+i)*PN + n] = hp[i];
        Al[(f8+i)*PN + n] = lp[i];
      }
    }
    #pragma unroll
    for (int u = 0; u < 3; ++u){
      int l = tid + u*256;
      int row = l >> 2, ch = (l & 3)*8;
      uint4 hv = *(const uint4*)(Qjh + (size_t)row*NN + nb + ch);
      uint4 lv = *(const uint4*)(Qjl + (size_t)row*NN + nb + ch);
      *(uint4*)(Bh3 + row*PN + ch) = hv;
      *(uint4*)(Bl3 + row*PN + ch) = lv;
    }
    __syncthreads();
    short8 a0h = *(const short8*)(Ah + (rowb      + l15)*PN + l4*8);
    short8 a1h = *(const short8*)(Ah + (rowb + 16 + l15)*PN + l4*8);
    short8 a0l = *(const short8*)(Al + (rowb      + l15)*PN + l4*8);
    short8 a1l = *(const short8*)(Al + (rowb + 16 + l15)*PN + l4*8);
    #pragma unroll
    for (int jj = 0; jj < 3; ++jj){
      #pragma unroll
      for (int cg = 0; cg < 2; ++cg){
        short8 bh = *(const short8*)(Bh3 + jj*64*PN + (colb + cg*16 + l15)*PN + l4*8);
        short8 bl = *(const short8*)(Bl3 + jj*64*PN + (colb + cg*16 + l15)*PN + l4*8);
        master[jj][0][cg] = __builtin_amdgcn_mfma_f32_16x16x32_bf16(a0h, bh, master[jj][0][cg], 0, 0, 0);
        master[jj][0][cg] = __builtin_amdgcn_mfma_f32_16x16x32_bf16(a0h, bl, master[jj][0][cg], 0, 0, 0);
        master[jj][0][cg] = __builtin_amdgcn_mfma_f32_16x16x32_bf16(a0l, bh, master[jj][0][cg], 0, 0, 0);
        master[jj][1][cg] = __builtin_amdgcn_mfma_f32_16x16x32_bf16(a1h, bh, master[jj][1][cg], 0, 0, 0);
        master[jj][1][cg] = __builtin_amdgcn_mfma_f32_16x16x32_bf16(a1h, bl, master[jj][1][cg], 0, 0, 0);
        master[jj][1][cg] = __builtin_amdgcn_mfma_f32_16x16x32_bf16(a1l, bh, master[jj][1][cg], 0, 0, 0);
      }
    }
  }

  float* dst = Ppart + (size_t)blockIdx.y * 76800;
  #pragma unroll
  for (int jj = 0; jj < 3; ++jj){
    int j = (jj == 2) ? 3 : jj;
    #pragma unroll
    for (int rg = 0; rg < 2; ++rg)
      #pragma unroll
      for (int cg = 0; cg < 2; ++cg)
        #pragma unroll
        for (int r = 0; r < 4; ++r){
          int f = rowb + rg*16 + l4*4 + r;
          int kcol = colb + cg*16 + l15;
          if (kcol < KK)
            dst[(size_t)((blockIdx.x*4 + j)*64 + f)*60 + kcol] = master[jj][rg][cg][r];
        }
  }
}

// Z[F x 60] from Ppart (BSPLIT private slabs); j=2 synthesized
__global__ void k_zasm(const float* __restrict__ Ppart, float* __restrict__ Z){
  int gid = blockIdx.x*blockDim.x + threadIdx.x;
  if (gid >= FF*KK) return;
  int f = gid / 60, k = gid - (gid/60)*60;
  int b = f >> 6, fi = f & 63;
  auto raw = [&](int t, int j)->float{
    size_t e = (size_t)((t*4 + j)*64 + fi)*60 + k;
    float s = 0.f;
    for (int bb = 0; bb < BSPLIT; ++bb) s += Ppart[(size_t)bb*76800 + e];
    return s;
  };
  auto fetch = [&](int t, int j)->float{
    if (j == 2) return 0.85f*raw(t,1) + 1.5e-6f*raw(t,0);
    return raw(t,j);
  };
  float val;
  if (b == 0)      val = raw(0,0);
  else if (b < 5)  val = fetch(1, b-1);
  else if (b < 9)  val = fetch(2, b-5);
  else if (b < 13) val = fetch(3, b-9);
  else if (b < 17) val = 0.85f*fetch(3, b-13) + 1.5e-6f*fetch(2, b-13);
  else             val = fetch(4, b-17);
  Z[gid] = val;
}

// ---------------- CholQR pieces ----------------
__global__ __launch_bounds__(256) void k_syrkp(const float* __restrict__ X, int nrows,
                                               float* __restrict__ Cpart){
  const int TTs = (nrows + 15)/16;
  int per = (TTs + gridDim.x - 1)/gridDim.x;
  int t0 = blockIdx.x*per;
  int t1 = t0 + per; if (t1 > TTs) t1 = TTs;
  __shared__ float Xs[16][64];
  int tid = threadIdx.x;
  int tx = tid & 15, ty = tid >> 4;
  float acc[4][4] = {};
  for (int tl = t0; tl < t1; ++tl){
    int nbase = tl*16;
    if (tid < 240){
      int n = tid / 15, ci = tid - (tid/15)*15;
      float4 v = make_float4(0.f,0.f,0.f,0.f);
      int gn = nbase + n;
      if (gn < nrows) v = *(const float4*)(X + (size_t)gn*KK + ci*4);
      *(float4*)&Xs[n][ci*4] = v;
    } else {
      int n = tid - 240;
      Xs[n][60]=0.f; Xs[n][61]=0.f; Xs[n][62]=0.f; Xs[n][63]=0.f;
    }
    __syncthreads();
    #pragma unroll
    for (int n = 0; n < 16; ++n){
      float4 a = *(const float4*)&Xs[n][tx*4];
      float4 b = *(const float4*)&Xs[n][ty*4];
      fma44(a, b, acc);
    }
    __syncthreads();
  }
  float* dst = Cpart + (size_t)blockIdx.x*3600;
  #pragma unroll
  for (int i = 0; i < 4; ++i){
    int r = tx*4 + i;
    #pragma unroll
    for (int j = 0; j < 4; ++j){
      int c = ty*4 + j;
      if (r < KK && c < KK) dst[r*KK + c] = acc[i][j];
    }
  }
}

__global__ void k_cred(const float* __restrict__ Cpart, int nparts, float* __restrict__ Cm){
  int gid = blockIdx.x*blockDim.x + threadIdx.x;
  if (gid >= 3600) return;
  float s = 0.f;
  for (int b = 0; b < nparts; ++b) s += Cpart[(size_t)b*3600 + gid];
  Cm[gid] = s;
}

__global__ __launch_bounds__(256) void k_cholinv(const float* __restrict__ Cin,
                                                 float* __restrict__ Rinv){
  __shared__ float R[60][65];
  __shared__ float Ri[60][65];
  __shared__ float Tmp[30][33];
  __shared__ float ridge;
  int t = threadIdx.x;
  for (int i = t; i < 3840; i += 256){
    int r = i >> 6, c = i & 63;
    if (c < 60) R[r][c] = Cin[r*60 + c];
  }
  __syncthreads();
  if (t == 0){
    float tr = 0.f;
    for (int i = 0; i < 60; ++i) tr += R[i][i];
    ridge = 1e-7f*(tr/60.f) + 1e-30f;
  }
  __syncthreads();
  if (t < 60) R[t][t] += ridge;
  __syncthreads();
  for (int j = 0; j < 60; ++j){
    float d  = fmaxf(R[j][j], 1e-30f);
    float dp = (j > 0) ? fmaxf(R[j-1][j-1], 1e-30f) : 1.f;
    float inv = 1.0f / d;
    float rsp = (j > 0) ? (1.0f / sqrtf(dp)) : 1.f;
    int nrow = 59 - j;
    for (int task = t; task < (nrow+1)*64; task += 256){
      int rr = task >> 6, i2 = task & 63;
      if (rr < nrow){
        int k = j + 1 + rr;
        if (i2 >= k && i2 < 60) R[k][i2] -= R[j][k]*R[j][i2]*inv;
      } else {
        if (j > 0 && i2 >= j-1 && i2 < 60) R[j-1][i2] *= rsp;
      }
    }
    __syncthreads();
  }
  if (t == 0) R[59][59] = sqrtf(fmaxf(R[59][59], 1e-30f));
  __syncthreads();
  for (int i = t; i < 3840; i += 256){ int r = i >> 6, c = i & 63; Ri[r][c] = 0.f; }
  __syncthreads();
  if (t < 60){
    int c = t;
    int lo = (c < 30) ? 0 : 30;
    Ri[c][c] = 1.0f / R[c][c];
    for (int i = c-1; i >= lo; --i){
      float s = 0.f;
      for (int k = i+1; k <= c; ++k) s += R[i][k]*Ri[k][c];
      Ri[i][c] = -s / R[i][i];
    }
  }
  __syncthreads();
  for (int idx2 = t; idx2 < 960; idx2 += 256){
    int r = idx2 >> 5, c = idx2 & 31;
    if (c < 30){
      float s = 0.f;
      for (int k = 0; k <= c; ++k) s += R[r][30+k]*Ri[30+k][30+c];
      Tmp[r][c] = s;
    }
  }
  __syncthreads();
  for (int idx2 = t; idx2 < 960; idx2 += 256){
    int r = idx2 >> 5, c = idx2 & 31;
    if (c < 30){
      float s = 0.f;
      for (int k = r; k < 30; ++k) s += Ri[r][k]*Tmp[k][c];
      Ri[r][30+c] = -s;
    }
  }
  __syncthreads();
  for (int i = t; i < 3600; i += 256) Rinv[i] = Ri[i/60][i%60];
}

__global__ __launch_bounds__(256) void k_cholinv2(const float* __restrict__ Gin,
                                                  float* __restrict__ Rinv){
  __shared__ float G[60][65];
  __shared__ float RN[60][65];
  __shared__ float T1[60][65];
  __shared__ float G2[60][65];
  __shared__ float Tmp[30][33];
  __shared__ float ridge;
  int t = threadIdx.x;
  for (int i = t; i < 3840; i += 256){
    int r = i >> 6, c = i & 63;
    if (c < 60){ G[r][c] = Gin[r*60 + c]; RN[r][c] = Rinv[r*60 + c]; }
  }
  __syncthreads();
  for (int o = t; o < 3600; o += 256){
    int i = o/60, j = o - (o/60)*60;
    float s = 0.f;
    for (int k = 0; k <= j; ++k) s = fmaf(G[i][k], RN[k][j], s);
    T1[i][j] = s;
  }
  __syncthreads();
  for (int o = t; o < 3600; o += 256){
    int i = o/60, j = o - (o/60)*60;
    float s = 0.f;
    for (int k = 0; k <= i; ++k) s = fmaf(RN[k][i], T1[k][j], s);
    G2[i][j] = s;
  }
  __syncthreads();
  if (t == 0){
    float tr = 0.f;
    for (int i = 0; i < 60; ++i) tr += G2[i][i];
    ridge = 1e-7f*(tr/60.f) + 1e-30f;
  }
  __syncthreads();
  if (t < 60) G2[t][t] += ridge;
  __syncthreads();
  for (int j = 0; j < 60; ++j){
    float d  = fmaxf(G2[j][j], 1e-30f);
    float dp = (j > 0) ? fmaxf(G2[j-1][j-1], 1e-30f) : 1.f;
    float inv = 1.0f / d;
    float rsp = (j > 0) ? (1.0f / sqrtf(dp)) : 1.f;
    int nrow = 59 - j;
    for (int task = t; task < (nrow+1)*64; task += 256){
      int rr = task >> 6, i2 = task & 63;
      if (rr < nrow){
        int k = j + 1 + rr;
        if (i2 >= k && i2 < 60) G2[k][i2] -= G2[j][k]*G2[j][i2]*inv;
      } else {
        if (j > 0 && i2 >= j-1 && i2 < 60) G2[j-1][i2] *= rsp;
      }
    }
    __syncthreads();
  }
  if (t == 0) G2[59][59] = sqrtf(fmaxf(G2[59][59], 1e-30f));
  __syncthreads();
  for (int i = t; i < 3840; i += 256){ int r = i >> 6, c = i & 63; T1[r][c] = 0.f; }
  __syncthreads();
  if (t < 60){
    int c = t;
    int lo = (c < 30) ? 0 : 30;
    T1[c][c] = 1.0f / G2[c][c];
    for (int i = c-1; i >= lo; --i){
      float s = 0.f;
      for (int k = i+1; k <= c; ++k) s += G2[i][k]*T1[k][c];
      T1[i][c] = -s / G2[i][i];
    }
  }
  __syncthreads();
  for (int idx2 = t; idx2 < 960; idx2 += 256){
    int r = idx2 >> 5, c = idx2 & 31;
    if (c < 30){
      float s = 0.f;
      for (int k = 0; k <= c; ++k) s += G2[r][30+k]*T1[30+k][30+c];
      Tmp[r][c] = s;
    }
  }
  __syncthreads();
  for (int idx2 = t; idx2 < 960; idx2 += 256){
    int r = idx2 >> 5, c = idx2 & 31;
    if (c < 30){
      float s = 0.f;
      for (int k = r; k < 30; ++k) s += T1[r][k]*Tmp[k][c];
      T1[r][30+c] = -s;
    }
  }
  __syncthreads();
  for (int o = t; o < 3600; o += 256){
    int i = o/60, j = o - (o/60)*60;
    float s = 0.f;
    if (i <= j){
      for (int k = i; k <= j; ++k) s = fmaf(RN[i][k], T1[k][j], s);
    }
    Rinv[o] = s;
  }
}

__global__ __launch_bounds__(256) void k_applyR(const float* Yin,
    const float* __restrict__ Rinv, float* Xout, int nrows){
  __shared__ float Rs[3600];
  for (int i = threadIdx.x; i < 3600; i += 256) Rs[i] = Rinv[i];
  __syncthreads();
  int w = threadIdx.x >> 6, lane = threadIdx.x & 63;
  #pragma unroll
  for (int r = 0; r < 4; ++r){
    int n = blockIdx.x*16 + w*4 + r;
    if (n >= nrows) continue;
    const float* y = Yin + (size_t)n*KK;
    float accv = 0.f;
    #pragma unroll 10
    for (int k2 = 0; k2 < KK; ++k2) accv = fmaf(y[k2], Rs[k2*KK + lane], accv);
    if (lane < KK) Xout[(size_t)n*KK + lane] = accv;
  }
}

__global__ void k_wb(const float* __restrict__ Z, const float* __restrict__ w,
                     float* __restrict__ WB){
  int gid = blockIdx.x*blockDim.x + threadIdx.x;
  if (gid >= KK*64) return;
  int r = gid >> 6, d = gid & 63;
  float acc = 0.f;
  for (int f = 0; f < FF; ++f) acc = fmaf(Z[(size_t)f*KK + r], w[(size_t)f*64 + d], acc);
  WB[gid] = acc;
}

// Jacobi eigensolver — two-pass, 3 sweeps (VERIFIED r10-r17; 2 sweeps failed r15)
__global__ __launch_bounds__(512) void k_jacobi(const float* __restrict__ Min,
                                                float* __restrict__ U50){
  __shared__ float A[60][65];
  __shared__ float Vv[60][65];
  __shared__ float cs[32], sn[32];
  __shared__ int pp[32], qq[32];
  __shared__ float ev[64];
  __shared__ int idx[64];
  int t = threadIdx.x;
  for (int i = t; i < 3840; i += 512){
    int r = i >> 6, c = i & 63;
    if (c < 60){ A[r][c] = Min[r*60 + c]; Vv[r][c] = (r == c) ? 1.f : 0.f; }
  }
  __syncthreads();
  for (int sweep = 0; sweep < 3; ++sweep){
    for (int round = 0; round < 59; ++round){
      if (t < 30){
        int i = t, j2 = 59 - t;
        int p = (i == 0) ? 0 : ((i - 1 + round) % 59 + 1);
        int q = ((j2 - 1 + round) % 59 + 1);
        if (p > q){ int tv = p; p = q; q = tv; }
        pp[t] = p; qq[t] = q;
        float app = A[p][p], aqq = A[q][q], apq = A[p][q];
        float c, s;
        if (fabsf(apq) < 1e-36f){ c = 1.f; s = 0.f; }
        else {
          float tau = (aqq - app) / (2.f * apq);
          float tt = ((tau >= 0.f) ? 1.f : -1.f) / (fabsf(tau) + sqrtf(1.f + tau*tau));
          c = 1.f / sqrtf(1.f + tt*tt);
          s = tt * c;
        }
        cs[t] = c; sn[t] = s;
      }
      __syncthreads();
      for (int task = t; task < 1920; task += 512){
        int k = task >> 6, i = task & 63;
        if (i < 60){
          int p = pp[k], q = qq[k];
          float c = cs[k], s = sn[k];
          float aip = A[i][p], aiq = A[i][q];
          A[i][p] = c*aip - s*aiq;  A[i][q] = s*aip + c*aiq;
          float vip = Vv[i][p], viq = Vv[i][q];
          Vv[i][p] = c*vip - s*viq; Vv[i][q] = s*vip + c*viq;
        }
      }
      __syncthreads();
      for (int task = t; task < 1920; task += 512){
        int k = task >> 6, i = task & 63;
        if (i < 60){
          int p = pp[k], q = qq[k];
          float c = cs[k], s = sn[k];
          float api = A[p][i], aqi = A[q][i];
          A[p][i] = c*api - s*aqi;  A[q][i] = s*api + c*aqi;
        }
      }
      __syncthreads();
    }
  }
  if (t < 60) ev[t] = A[t][t];
  __syncthreads();
  if (t < 60){
    float mine = ev[t];
    int rank = 0;
    for (int j = 0; j < 60; ++j){
      float o = ev[j];
      if (o > mine || (o == mine && j < t)) ++rank;
    }
    if (rank < RK) idx[rank] = t;
  }
  __syncthreads();
  for (int i2 = t; i2 < 60*RK; i2 += 512){
    int r = i2 / RK, c = i2 - (i2/RK)*RK;
    U50[i2] = Vv[r][idx[c]];
  }
}

// fused projector chain + Rinv fold: TW1 = Rinv · (U50 U50^T WB W1)
__global__ __launch_bounds__(256) void k_chain(const float* __restrict__ U50,
    const float* __restrict__ WB, const float* __restrict__ W1,
    const float* __restrict__ Rinv, float* __restrict__ TW1){
  __shared__ float Us[60][52];
  __shared__ float WBs[60][64];
  __shared__ float G[50][64];
  __shared__ float Ts[60][64];
  __shared__ float Tm2[60][33];
  int t = threadIdx.x;
  for (int i = t; i < 60*RK; i += 256) Us[i/RK][i%RK] = U50[i];
  for (int i = t; i < 3840; i += 256) WBs[i>>6][i&63] = WB[i];
  __syncthreads();
  for (int o = t; o < RK*64; o += 256){
    int r = o >> 6, d = o & 63;
    float acc = 0.f;
    #pragma unroll 10
    for (int i = 0; i < KK; ++i) acc = fmaf(Us[i][r], WBs[i][d], acc);
    G[r][d] = acc;
  }
  __syncthreads();
  for (int o = t; o < KK*64; o += 256){
    int i = o >> 6, d = o & 63;
    float acc = 0.f;
    #pragma unroll 10
    for (int r = 0; r < RK; ++r) acc = fmaf(Us[i][r], G[r][d], acc);
    Ts[i][d] = acc;
  }
  __syncthreads();
  for (int o = t; o < KK*HIDN; o += 256){
    int i = o >> 5, j = o & 31;
    float acc = 0.f;
    #pragma unroll 8
    for (int d = 0; d < 64; ++d) acc = fmaf(Ts[i][d], W1[d*HIDN + j], acc);
    Tm2[i][j] = acc;
  }
  __syncthreads();
  for (int o = t; o < KK*HIDN; o += 256){
    int i = o >> 5, j = o & 31;
    float acc = 0.f;
    for (int k = i; k < KK; ++k) acc = fmaf(Rinv[i*KK + k], Tm2[k][j], acc);
    TW1[o] = acc;
  }
}

__global__ __launch_bounds__(256) void k_hid(const float* __restrict__ Q,
    const float* __restrict__ TW1, const float* __restrict__ b1, float* __restrict__ hid){
  __shared__ float Ts[KK*HIDN];
  __shared__ float bs[HIDN];
  for (int i = threadIdx.x; i < KK*HIDN; i += 256) Ts[i] = TW1[i];
  if (threadIdx.x < HIDN) bs[threadIdx.x] = b1[threadIdx.x];
  __syncthreads();
  int gid = blockIdx.x*256 + threadIdx.x;
  if (gid >= NN*HIDN) return;
  int n = gid >> 5, j = gid & 31;
  const float* q = Q + (size_t)n*KK;
  float a = bs[j];
  #pragma unroll 10
  for (int k2 = 0; k2 < KK; ++k2) a = fmaf(q[k2], Ts[k2*HIDN + j], a);
  hid[gid] = (a >= 0.f) ? a : 0.01f*a;
}

__global__ void k_gstart(const int* __restrict__ gids, int* __restrict__ gst){
  int g = blockIdx.x*blockDim.x + threadIdx.x;
  if (g > GG) return;
  if (g == GG){ gst[GG] = NN; return; }
  int lo = 0, hi = NN;
  while (lo < hi){ int mid = (lo + hi) >> 1; if (gids[mid] < g) lo = mid + 1; else hi = mid; }
  gst[g] = lo;
}

__global__ __launch_bounds__(256) void k_gpool(const float* __restrict__ hid,
    const int* __restrict__ gst, float* __restrict__ pooled){
  int g = blockIdx.x;
  __shared__ float part[8][32];
  int w = threadIdx.x >> 5, lane = threadIdx.x & 31;
  int s = gst[g], e = gst[g+1];
  float acc = 0.f;
  for (int n = s + w; n < e; n += 8)
    acc += hid[(size_t)n*HIDN + lane];
  part[w][lane] = acc;
  __syncthreads();
  if (w == 0){
    float v = 0.f;
    #pragma unroll
    for (int i = 0; i < 8; ++i) v += part[i][lane];
    pooled[g*HIDN + lane] = v;
  }
}

__global__ void k_out(const float* __restrict__ pooled, const float* __restrict__ W2,
                      float* __restrict__ out){
  int gid = blockIdx.x*blockDim.x + threadIdx.x;
  if (gid >= GG*NCL) return;
  int g = gid / NCL, c = gid - (gid/NCL)*NCL;
  const float* p = pooled + g*HIDN;
  float acc = 0.f;
  #pragma unroll
  for (int k = 0; k < HIDN; ++k) acc = fmaf(p[k], W2[(size_t)k*NCL + c], acc);
  out[gid] = acc;
}

// ---------------- host ----------------
extern "C" void kernel_launch(void* const* d_in, const int* in_sizes, int n_in,
                              void* d_out, int out_size, void* d_ws, size_t ws_size,
                              hipStream_t stream){
  (void)in_sizes; (void)n_in; (void)out_size;
  const float* x   = (const float*)d_in[0];
  const int*  rows = (const int*)d_in[1];
  const int*  cols = (const int*)d_in[2];
  const int*  gids = (const int*)d_in[3];
  const float* wM  = (const float*)d_in[5];
  const float* W1  = (const float*)d_in[6];
  const float* b1  = (const float*)d_in[7];
  const float* W2  = (const float*)d_in[8];
  float* out = (float*)d_out;

  char* base = (char*)d_ws;
  size_t off = 0;
  auto alloc = [&](size_t bytes)->char*{
    off = (off + 255) & ~(size_t)255;
    char* p = base + off; off += bytes; return p;
  };
  float* ax    = (float*)alloc((size_t)NN*64*4);        // dead after hop2
  int*   csr   = (int*)  alloc((size_t)EE*4);           // adjacent; dead after hop2
  unsigned short* Qjh = (unsigned short*)ax;            // 38.4MB overlay of ax+csr
  unsigned short* xh  = (unsigned short*)alloc((size_t)NN*64*2);
  unsigned short* xl  = (unsigned short*)alloc((size_t)NN*64*2);
  unsigned short* axh = (unsigned short*)alloc((size_t)NN*64*2);
  unsigned short* axl = (unsigned short*)alloc((size_t)NN*64*2);
  unsigned short* s0h = (unsigned short*)alloc((size_t)NN*64*2);
  unsigned short* s0l = (unsigned short*)alloc((size_t)NN*64*2);
  unsigned short* s1h = (unsigned short*)alloc((size_t)NN*64*2);
  unsigned short* s1l = (unsigned short*)alloc((size_t)NN*64*2);
  unsigned short* s3h = (unsigned short*)alloc((size_t)NN*64*2);
  unsigned short* s3l = (unsigned short*)alloc((size_t)NN*64*2);
  float* Y     = (float*)alloc((size_t)NN*KK*4);
  unsigned short* Qjl = (unsigned short*)alloc((size_t)3*64*NN*2);  // reused as hid later
  float* Ppart = (float*)alloc((size_t)BSPLIT*76800*4);
  unsigned short* Beh = (unsigned short*)alloc((size_t)20*4096*2);
  unsigned short* Bel = (unsigned short*)alloc((size_t)20*4096*2);
  float* Om    = (float*)alloc((size_t)FF*KK*4);
  float* Zf    = (float*)alloc((size_t)FF*KK*4);
  float* Cm    = (float*)alloc(3600*4);
  float* Rinv  = (float*)alloc(3600*4);
  float* Mm    = (float*)alloc(3600*4);
  float* U50   = (float*)alloc(60*RK*4);
  float* WB    = (float*)alloc(KK*64*4);
  float* TW1   = (float*)alloc(KK*HIDN*4);
  float* pooled= (float*)alloc((size_t)GG*HIDN*4);
  float* r1    = (float*)alloc((size_t)NN*4);
  float* r2    = (float*)alloc((size_t)NN*4);
  int* cnt     = (int*)alloc((size_t)NN*4);
  int* rowptr  = (int*)alloc((size_t)(NN+1)*4);
  int* tmpc    = (int*)alloc((size_t)NN*4);
  int* gst     = (int*)alloc((size_t)(GG+1)*4);
  int* bsums   = (int*)alloc(256*4);
  float* hid   = (float*)Qjl;
  float* Cpart = Ppart;
  size_t off_base = off;
  if (off_base > ws_size) return;

  // ---- granular TT: fit as many transposed tensors as the ws holds ----
  const size_t perT = (size_t)64*NN*2;   // 12.8 MB per tensor per (hi|lo)
  int nTT = 0;
  if (ws_size > off_base + 1024){
    size_t avail = ws_size - off_base - 1024;   // margin for two 256-pads
    nTT = (int)(avail / (2*perT));
    if (nTT > 5) nTT = 5;
  }
  unsigned short* TTh = nullptr;
  unsigned short* TTl = nullptr;
  if (nTT > 0){
    TTh = (unsigned short*)alloc(perT * (size_t)nTT);
    TTl = (unsigned short*)alloc(perT * (size_t)nTT);
    if (off > ws_size){ nTT = 0; TTh = nullptr; TTl = nullptr; }  // paranoia
  }
  int tstart = 5 - nTT;

  const int SCAN_B = (NN + 1023) / 1024;

  // ---- graph prep ----
  hipMemsetAsync(cnt, 0, (size_t)NN*4, stream);
  k_count<<<(EE+255)/256, 256, 0, stream>>>(rows, cnt);
  k_scan1<<<SCAN_B, 1024, 0, stream>>>(cnt, rowptr, bsums);
  k_scan2<<<1, 64, 0, stream>>>(bsums, SCAN_B);
  k_scan3<<<(NN+255)/256, 256, 0, stream>>>(cnt, bsums, rowptr);
  hipMemsetAsync(tmpc, 0, (size_t)NN*4, stream);
  k_scatter<<<(EE+255)/256, 256, 0, stream>>>(rows, cols, rowptr, tmpc, csr);
  k_degr<<<(NN+255)/256, 256, 0, stream>>>(cnt, r1, r2);

  // ---- base tensors (+ hi/lo); ax/csr dead after hop2 ----
  k_xcvt<<<(NN*64+255)/256, 256, 0, stream>>>(x, xh, xl);
  k_hop1<<<(NN+3)/4, 256, 0, stream>>>(x, rowptr, csr, ax, axh, axl);
  k_hop2<<<(NN+3)/4, 256, 0, stream>>>(rowptr, csr, ax, r1, r2, s0h, s0l, s1h, s1l, s3h, s3l);
  if (nTT > 0)
    k_tcvt<<<dim3((NN+63)/64, nTT), 256, 0, stream>>>(xh, xl, axh, axl, s0h, s0l,
                                                      s1h, s1l, s3h, s3l, tstart, TTh, TTl);

  // ---- omega ----
  k_omega<<<(FF*KK+255)/256, 256, 0, stream>>>(Om);

  auto fwdg = [&](){    // fwd + fused gram + fused Qj emission
    hipMemsetAsync(Cpart, 0, (size_t)GSL*3600*4, stream);
    k_fwd<<<(NN+63)/64, 256, 0, stream>>>(xh, xl, axh, axl, s0h, s0l, s1h, s1l, s3h, s3l,
                                          Beh, Bel, r1, r2, Y, Cpart, Qjh, Qjl);
  };
  auto bwd = [&](){     // uses Qj emitted by the preceding fwdg (Y unchanged in between)
    k_bwd<<<dim3(5, BSPLIT), 256, 0, stream>>>(xh, xl, axh, axl, s0h, s0l, s1h, s1l,
                                               s3h, s3l, TTh, TTl, tstart, Qjh, Qjl, Ppart);
    k_zasm<<<(FF*KK+255)/256, 256, 0, stream>>>(Ppart, Zf);
  };

  // ---- Y0 = h @ omega (+gram +Qj) ----
  k_beff<<<(20*4096+255)/256, 256, 0, stream>>>(Om, Beh, Bel);
  fwdg();

  // ---- power iterations ----
  for (int it = 0; it < 4; ++it){
    k_cred<<<15, 256, 0, stream>>>(Cpart, GSL, Cm);
    k_cholinv<<<1, 256, 0, stream>>>(Cm, Rinv);                  // RinvN
    bwd();                                                       // Zraw = h^T Y
    k_syrkp<<<84, 256, 0, stream>>>(Zf, FF, Cpart);
    k_cred<<<15, 256, 0, stream>>>(Cpart, 84, Cm);
    k_cholinv2<<<1, 256, 0, stream>>>(Cm, Rinv);                 // Rinv := Rtot
    k_beffT<<<20, 256, 0, stream>>>(Zf, Rinv, Beh, Bel);
    fwdg();                                                      // Y = h Qf (+gram +Qj)
  }

  // ---- final: RinvN; Zf = (h^T Y)·RinvN ----
  k_cred<<<15, 256, 0, stream>>>(Cpart, GSL, Cm);
  k_cholinv<<<1, 256, 0, stream>>>(Cm, Rinv);
  bwd();                                                         // Zraw = h^T Y
  k_applyR<<<(FF+15)/16, 256, 0, stream>>>(Zf, Rinv, Zf, FF);    // Zf = Zraw·RinvN
  k_syrkp<<<84, 256, 0, stream>>>(Zf, FF, Cpart);
  k_cred<<<15, 256, 0, stream>>>(Cpart, 84, Mm);
  k_wb<<<(KK*64+255)/256, 256, 0, stream>>>(Zf, wM, WB);

  // ---- eigensolve + projector chain (Rinv folded into TW1) ----
  k_jacobi<<<1, 512, 0, stream>>>(Mm, U50);
  k_chain<<<1, 256, 0, stream>>>(U50, WB, W1, Rinv, TW1);

  // ---- MLP + pooling (hid overlays Qjl) ----
  k_hid<<<(NN*HIDN+255)/256, 256, 0, stream>>>(Y, TW1, b1, hid);
  k_gstart<<<1, 256, 0, stream>>>(gids, gst);
  k_gpool<<<GG, 256, 0, stream>>>(hid, gst, pooled);
  k_out<<<(GG*NCL+255)/256, 256, 0, stream>>>(pooled, W2, out);
}

// Round 19
// 3883.478 us; speedup vs baseline: 1.0154x; 1.0154x over previous
//
#include <hip/hip_runtime.h>

#define NN   100000
#define DD   64
#define EE   3200000
#define GG   128
#define FF   1344
#define KK   60
#define RK   50
#define HIDN 32
#define NCL  696
#define BSPLIT 96
#define GSL  64
#define PN   40

// OMEGA xor-fold VERIFIED r3. JACOBI: 3 sweeps VERIFIED r10-r18 (absmax 48); 2 sweeps FAILED r15.
// split-bf16 MFMA fwd/bwd VERIFIED r8/r9. hi/lo precompute r10+. Qj fused into k_fwd r17.
// LESSON r16: slab-atomic bwd net-negative. LESSON r18: ws ~= 256MiB -> nTT=0, scatter path live.
// r19: A-tile LDS XOR-swizzle in k_bwd (write 16-way -> 4-way bank conflict; reads b128 unswizzle).

typedef short short8 __attribute__((ext_vector_type(8)));
typedef float f32x4 __attribute__((ext_vector_type(4)));

__device__ __forceinline__ unsigned short f2bf(float x){
  unsigned u = __float_as_uint(x);
  unsigned r = u + 0x7fffu + ((u>>16)&1u);
  return (unsigned short)(r>>16);
}
__device__ __forceinline__ float bf2f(unsigned short h){
  return __uint_as_float(((unsigned)h)<<16);
}
__device__ __forceinline__ int aswz(int f, int nblk){ return nblk ^ ((f>>3)&3); }

// ---------------- threefry + erfinv ----------------
__device__ __forceinline__ unsigned rotl32(unsigned x, unsigned r){ return (x<<r)|(x>>(32u-r)); }

__device__ __forceinline__ void threefry(unsigned& x0, unsigned& x1){
  const unsigned ks0 = 0u, ks1 = 42u, ks2 = 0x1BD11BDAu ^ 0u ^ 42u;
  unsigned ks[3] = {ks0, ks1, ks2};
  const unsigned rotA[4] = {13u,15u,26u,6u};
  const unsigned rotB[4] = {17u,29u,16u,24u};
  x0 += ks0; x1 += ks1;
  #pragma unroll
  for (int i = 0; i < 5; ++i){
    #pragma unroll
    for (int j = 0; j < 4; ++j){
      unsigned r = (i & 1) ? rotB[j] : rotA[j];
      x0 += x1; x1 = rotl32(x1, r); x1 ^= x0;
    }
    x0 += ks[(i+1)%3]; x1 += ks[(i+2)%3] + (unsigned)(i+1);
  }
}

__device__ __forceinline__ float bits_to_normal(unsigned bits){
  unsigned mant = bits >> 9;
  float f; { unsigned fb = 0x3f800000u | mant; f = __uint_as_float(fb); }
  f -= 1.0f;
  const float lo = -0.99999994f;
  float u = fmaf(f, 2.0f, lo);
  u = fmaxf(lo, u);
  float w = -log1pf(-u*u);
  float p;
  if (w < 5.0f){
    w -= 2.5f;
    p = 2.81022636e-08f;
    p = fmaf(p, w, 3.43273939e-07f);
    p = fmaf(p, w, -3.5233877e-06f);
    p = fmaf(p, w, -4.39150654e-06f);
    p = fmaf(p, w, 0.00021858087f);
    p = fmaf(p, w, -0.00125372503f);
    p = fmaf(p, w, -0.00417768164f);
    p = fmaf(p, w, 0.246640727f);
    p = fmaf(p, w, 1.50140941f);
  } else {
    w = sqrtf(w) - 3.0f;
    p = -0.000200214257f;
    p = fmaf(p, w, 0.000100950558f);
    p = fmaf(p, w, 0.00134934322f);
    p = fmaf(p, w, -0.00367342844f);
    p = fmaf(p, w, 0.00573950773f);
    p = fmaf(p, w, -0.0076224613f);
    p = fmaf(p, w, 0.00943887047f);
    p = fmaf(p, w, 1.00167406f);
    p = fmaf(p, w, 2.83297682f);
  }
  return 1.41421356f * (p * u);
}

__global__ void k_omega(float* __restrict__ om){
  int i = blockIdx.x*blockDim.x + threadIdx.x;
  if (i >= FF*KK) return;
  unsigned x0 = 0u, x1 = (unsigned)i;
  threefry(x0, x1);
  om[i] = bits_to_normal(x0 ^ x1);
}

// ---------------- CSR build ----------------
__global__ void k_count(const int* __restrict__ rows, int* __restrict__ cnt){
  int e = blockIdx.x*blockDim.x + threadIdx.x;
  if (e < EE) atomicAdd(&cnt[rows[e]], 1);
}

__global__ __launch_bounds__(1024) void k_scan1(const int* __restrict__ cnt,
    int* __restrict__ incl, int* __restrict__ bsums){
  __shared__ int buf[1024];
  int i = blockIdx.x*1024 + threadIdx.x;
  int v = (i < NN) ? cnt[i] : 0;
  buf[threadIdx.x] = v; __syncthreads();
  for (int ofs = 1; ofs < 1024; ofs <<= 1){
    int add = (threadIdx.x >= (unsigned)ofs) ? buf[threadIdx.x - ofs] : 0;
    __syncthreads();
    buf[threadIdx.x] += add;
    __syncthreads();
  }
  if (i < NN) incl[i] = buf[threadIdx.x];
  if (threadIdx.x == 1023) bsums[blockIdx.x] = buf[1023];
}

__global__ void k_scan2(int* __restrict__ bsums, int nb){
  if (threadIdx.x == 0){
    int run = 0;
    for (int i = 0; i < nb; ++i){ int v = bsums[i]; bsums[i] = run; run += v; }
  }
}

__global__ void k_scan3(const int* __restrict__ cnt, const int* __restrict__ bsums,
                        int* __restrict__ rowptr){
  int i = blockIdx.x*blockDim.x + threadIdx.x;
  if (i >= NN) return;
  int incl = rowptr[i];
  int ex = incl - cnt[i] + bsums[i >> 10];
  rowptr[i] = ex;
  if (i == NN-1) rowptr[NN] = ex + cnt[i];
}

__global__ void k_scatter(const int* __restrict__ rows, const int* __restrict__ cols,
                          const int* __restrict__ rowptr, int* __restrict__ tmpc,
                          int* __restrict__ csr){
  int e = blockIdx.x*blockDim.x + threadIdx.x;
  if (e >= EE) return;
  int r = rows[e];
  int p = atomicAdd(&tmpc[r], 1);
  csr[rowptr[r] + p] = cols[e];
}

__global__ void k_degr(const int* __restrict__ cnt, float* __restrict__ r1, float* __restrict__ r2){
  int i = blockIdx.x*blockDim.x + threadIdx.x;
  if (i >= NN) return;
  int d = cnt[i];
  float fd = (float)d;
  r1[i] = (d > 0) ? 1.0f/fd : 1.0f;
  r2[i] = 1.0f/(fd + 1e-5f);
}

// ---------------- x -> hi/lo ----------------
__global__ void k_xcvt(const float* __restrict__ x,
                       unsigned short* __restrict__ xh, unsigned short* __restrict__ xl){
  int gid = blockIdx.x*blockDim.x + threadIdx.x;
  if (gid >= NN*64) return;
  float v = x[gid];
  unsigned short h = f2bf(v);
  xh[gid] = h;
  xl[gid] = f2bf(v - bf2f(h));
}

// ---------------- propagation ----------------
__global__ __launch_bounds__(256) void k_hop1(const float* __restrict__ x,
    const int* __restrict__ rp, const int* __restrict__ cc, float* __restrict__ ax,
    unsigned short* __restrict__ axh, unsigned short* __restrict__ axl){
  int n = blockIdx.x*4 + (threadIdx.x >> 6);
  int lane = threadIdx.x & 63;
  if (n >= NN) return;
  int s = rp[n], e = rp[n+1];
  float acc = 0.f;
  int idx = s;
  for (; idx + 8 <= e; idx += 8){
    int c0 = cc[idx], c1 = cc[idx+1], c2 = cc[idx+2], c3 = cc[idx+3];
    int c4 = cc[idx+4], c5 = cc[idx+5], c6 = cc[idx+6], c7 = cc[idx+7];
    float v0 = x[(size_t)c0*64 + lane];
    float v1 = x[(size_t)c1*64 + lane];
    float v2 = x[(size_t)c2*64 + lane];
    float v3 = x[(size_t)c3*64 + lane];
    float v4 = x[(size_t)c4*64 + lane];
    float v5 = x[(size_t)c5*64 + lane];
    float v6 = x[(size_t)c6*64 + lane];
    float v7 = x[(size_t)c7*64 + lane];
    acc += ((v0 + v1) + (v2 + v3)) + ((v4 + v5) + (v6 + v7));
  }
  for (; idx < e; ++idx) acc += x[(size_t)cc[idx]*64 + lane];
  size_t o = (size_t)n*64 + lane;
  ax[o] = acc;
  unsigned short h = f2bf(acc);
  axh[o] = h;
  axl[o] = f2bf(acc - bf2f(h));
}

__global__ __launch_bounds__(256) void k_hop2(const int* __restrict__ rp, const int* __restrict__ cc,
    const float* __restrict__ ax, const float* __restrict__ r1, const float* __restrict__ r2,
    unsigned short* __restrict__ s0h, unsigned short* __restrict__ s0l,
    unsigned short* __restrict__ s1h, unsigned short* __restrict__ s1l,
    unsigned short* __restrict__ s3h, unsigned short* __restrict__ s3l){
  int n = blockIdx.x*4 + (threadIdx.x >> 6);
  int lane = threadIdx.x & 63;
  if (n >= NN) return;
  int s = rp[n], e = rp[n+1];
  float v_s0 = 0.f, v_s1 = 0.f, v_s3 = 0.f;
  int idx = s;
  for (; idx + 8 <= e; idx += 8){
    int c0 = cc[idx], c1 = cc[idx+1], c2 = cc[idx+2], c3 = cc[idx+3];
    int c4 = cc[idx+4], c5 = cc[idx+5], c6 = cc[idx+6], c7 = cc[idx+7];
    float v0 = ax[(size_t)c0*64 + lane], a0 = r1[c0], b0 = r2[c0];
    float v1 = ax[(size_t)c1*64 + lane], a1 = r1[c1], b1 = r2[c1];
    float v2 = ax[(size_t)c2*64 + lane], a2 = r1[c2], b2 = r2[c2];
    float v3 = ax[(size_t)c3*64 + lane], a3 = r1[c3], b3 = r2[c3];
    float v4 = ax[(size_t)c4*64 + lane], a4 = r1[c4], b4 = r2[c4];
    float v5 = ax[(size_t)c5*64 + lane], a5 = r1[c5], b5 = r2[c5];
    float v6 = ax[(size_t)c6*64 + lane], a6 = r1[c6], b6 = r2[c6];
    float v7 = ax[(size_t)c7*64 + lane], a7 = r1[c7], b7 = r2[c7];
    v_s0 += ((v0 + v1) + (v2 + v3)) + ((v4 + v5) + (v6 + v7));
    v_s1 = fmaf(v0,a0,fmaf(v1,a1,fmaf(v2,a2,fmaf(v3,a3,v_s1))));
    v_s1 = fmaf(v4,a4,fmaf(v5,a5,fmaf(v6,a6,fmaf(v7,a7,v_s1))));
    v_s3 = fmaf(v0,b0,fmaf(v1,b1,fmaf(v2,b2,fmaf(v3,b3,v_s3))));
    v_s3 = fmaf(v4,b4,fmaf(v5,b5,fmaf(v6,b6,fmaf(v7,b7,v_s3))));
  }
  for (; idx < e; ++idx){
    int c = cc[idx];
    float v = ax[(size_t)c*64 + lane];
    v_s0 += v;
    v_s1 = fmaf(v, r1[c], v_s1);
    v_s3 = fmaf(v, r2[c], v_s3);
  }
  size_t o = (size_t)n*64 + lane;
  unsigned short h0 = f2bf(v_s0);
  s0h[o] = h0; s0l[o] = f2bf(v_s0 - bf2f(h0));
  unsigned short h1 = f2bf(v_s1);
  s1h[o] = h1; s1l[o] = f2bf(v_s1 - bf2f(h1));
  unsigned short h3 = f2bf(v_s3);
  s3h[o] = h3; s3l[o] = f2bf(v_s3 - bf2f(h3));
}

// ---------------- one-time: TT[rel*64+f][n] = T_{tstart+rel} hi/lo transposed ----------------
__global__ __launch_bounds__(256) void k_tcvt(
    const unsigned short* __restrict__ xh, const unsigned short* __restrict__ xl,
    const unsigned short* __restrict__ axh, const unsigned short* __restrict__ axl,
    const unsigned short* __restrict__ s0h, const unsigned short* __restrict__ s0l,
    const unsigned short* __restrict__ s1h, const unsigned short* __restrict__ s1l,
    const unsigned short* __restrict__ s3h, const unsigned short* __restrict__ s3l,
    int tstart,
    unsigned short* __restrict__ TTh, unsigned short* __restrict__ TTl){
  __shared__ unsigned short Sh[64][72];
  __shared__ unsigned short Sl[64][72];
  int rel = blockIdx.y;
  int t = tstart + rel;
  const unsigned short* inh = (t==0)?xh:(t==1)?axh:(t==2)?s0h:(t==3)?s1h:s3h;
  const unsigned short* inl = (t==0)?xl:(t==1)?axl:(t==2)?s0l:(t==3)?s1l:s3l;
  int n0 = blockIdx.x*64;
  int tid = threadIdx.x;
  #pragma unroll
  for (int l = 0; l < 2; ++l){
    int li = tid + l*256;
    int n = li >> 3, f8 = (li & 7)*8;
    int gn = n0 + n;
    uint4 hv = make_uint4(0,0,0,0), lv = make_uint4(0,0,0,0);
    if (gn < NN){
      hv = *(const uint4*)(inh + (size_t)gn*64 + f8);
      lv = *(const uint4*)(inl + (size_t)gn*64 + f8);
    }
    *(uint4*)(&Sh[n][f8]) = hv;
    *(uint4*)(&Sl[n][f8]) = lv;
  }
  __syncthreads();
  #pragma unroll
  for (int l = 0; l < 2; ++l){
    int li = tid + l*256;
    int f = li >> 3, ch = (li & 7)*8;
    int gn0 = n0 + ch;
    if (gn0 + 8 <= NN){
      unsigned short hv[8], lv2[8];
      #pragma unroll
      for (int i = 0; i < 8; ++i){ hv[i] = Sh[ch+i][f]; lv2[i] = Sl[ch+i][f]; }
      *(uint4*)(TTh + (size_t)(rel*64+f)*NN + gn0) = *(uint4*)hv;
      *(uint4*)(TTl + (size_t)(rel*64+f)*NN + gn0) = *(uint4*)lv2;
    }
  }
}

// ---------------- Beff build ----------------
__global__ void k_beff(const float* __restrict__ B,
                       unsigned short* __restrict__ Beh, unsigned short* __restrict__ Bel){
  int gid = blockIdx.x*blockDim.x + threadIdx.x;
  if (gid >= 20*4096) return;
  int p = gid >> 12;
  int rem = gid & 4095;
  int c = rem >> 6, r = rem & 63;
  int t = p >> 2, j = p & 3;
  float val = 0.f;
  if (c < KK){
    if (t == 0)      val = (j == 0) ? B[(0*64 + r)*60 + c] : 0.f;
    else if (t == 1) val = B[((1+j)*64 + r)*60 + c];
    else if (t == 2) val = B[((5+j)*64 + r)*60 + c] + 1.5e-6f*B[((13+j)*64 + r)*60 + c];
    else if (t == 3) val = B[((9+j)*64 + r)*60 + c] + 0.85f  *B[((13+j)*64 + r)*60 + c];
    else             val = B[((17+j)*64 + r)*60 + c];
  }
  unsigned short h = f2bf(val);
  Beh[gid] = h;
  Bel[gid] = f2bf(val - bf2f(h));
}

__global__ __launch_bounds__(256) void k_beffT(const float* __restrict__ Z,
    const float* __restrict__ Rtot,
    unsigned short* __restrict__ Beh, unsigned short* __restrict__ Bel){
  __shared__ float Br[64][61];
  __shared__ float Rt[60][64];
  int p = blockIdx.x;
  int t2 = p >> 2, j = p & 3;
  int tid = threadIdx.x;
  if (t2 == 0 && j != 0){
    for (int o = tid; o < 4096; o += 256){ Beh[(size_t)p*4096 + o] = 0; Bel[(size_t)p*4096 + o] = 0; }
    return;
  }
  for (int i = tid; i < 3840; i += 256){
    int r = i >> 6, c = i & 63;
    if (c < 60) Rt[r][c] = Rtot[r*60 + c];
  }
  for (int o = tid; o < 64*60; o += 256){
    int r = o / 60, k = o - (o/60)*60;
    float v;
    if (t2 == 0)      v = Z[(0*64 + r)*60 + k];
    else if (t2 == 1) v = Z[((1+j)*64 + r)*60 + k];
    else if (t2 == 2) v = Z[((5+j)*64 + r)*60 + k] + 1.5e-6f*Z[((13+j)*64 + r)*60 + k];
    else if (t2 == 3) v = Z[((9+j)*64 + r)*60 + k] + 0.85f  *Z[((13+j)*64 + r)*60 + k];
    else              v = Z[((17+j)*64 + r)*60 + k];
    Br[r][k] = v;
  }
  __syncthreads();
  for (int o = tid; o < 4096; o += 256){
    int c = o >> 6, r = o & 63;
    float s = 0.f;
    if (c < KK){
      #pragma unroll 10
      for (int kp = 0; kp < 60; ++kp) s = fmaf(Br[r][kp], Rt[kp][c], s);
    }
    unsigned short h = f2bf(s);
    Beh[(size_t)p*4096 + o] = h;
    Bel[(size_t)p*4096 + o] = f2bf(s - bf2f(h));
  }
}

// ---------------- forward: split-bf16 MFMA + fused block-gram + fused Qj emission ----------------
__device__ __forceinline__ void fma44(const float4 a, const float4 b, float (&acc)[4][4]){
  acc[0][0] = fmaf(a.x,b.x,acc[0][0]); acc[0][1] = fmaf(a.x,b.y,acc[0][1]);
  acc[0][2] = fmaf(a.x,b.z,acc[0][2]); acc[0][3] = fmaf(a.x,b.w,acc[0][3]);
  acc[1][0] = fmaf(a.y,b.x,acc[1][0]); acc[1][1] = fmaf(a.y,b.y,acc[1][1]);
  acc[1][2] = fmaf(a.y,b.z,acc[1][2]); acc[1][3] = fmaf(a.y,b.w,acc[1][3]);
  acc[2][0] = fmaf(a.z,b.x,acc[2][0]); acc[2][1] = fmaf(a.z,b.y,acc[2][1]);
  acc[2][2] = fmaf(a.z,b.z,acc[2][2]); acc[2][3] = fmaf(a.z,b.w,acc[2][3]);
  acc[3][0] = fmaf(a.w,b.x,acc[3][0]); acc[3][1] = fmaf(a.w,b.y,acc[3][1]);
  acc[3][2] = fmaf(a.w,b.z,acc[3][2]); acc[3][3] = fmaf(a.w,b.w,acc[3][3]);
}

__global__ __launch_bounds__(256) void k_fwd(
    const unsigned short* __restrict__ xh, const unsigned short* __restrict__ xl,
    const unsigned short* __restrict__ axh, const unsigned short* __restrict__ axl,
    const unsigned short* __restrict__ s0h, const unsigned short* __restrict__ s0l,
    const unsigned short* __restrict__ s1h, const unsigned short* __restrict__ s1l,
    const unsigned short* __restrict__ s3h, const unsigned short* __restrict__ s3l,
    const unsigned short* __restrict__ Beh, const unsigned short* __restrict__ Bel,
    const float* __restrict__ r1, const float* __restrict__ r2,
    float* __restrict__ Y, float* __restrict__ Cpart,
    unsigned short* __restrict__ Qjh, unsigned short* __restrict__ Qjl){
  __shared__ __align__(16) unsigned short AB[4*64*72];
  __shared__ float cS[4][64];
  unsigned short* Ah = AB;
  unsigned short* Al = AB + 64*72;
  unsigned short* Bh = AB + 2*64*72;
  unsigned short* Bl = AB + 3*64*72;
  float* As2 = (float*)AB;
  const unsigned short* Tsh[5] = {xh, axh, s0h, s1h, s3h};
  const unsigned short* Tsl[5] = {xl, axl, s0l, s1l, s3l};
  int n0 = blockIdx.x*64;
  int tid = threadIdx.x;
  int lane = tid & 63, wid = tid >> 6;
  int rowb = (wid & 1)*32, colb = (wid >> 1)*32;
  int l15 = lane & 15, l4 = lane >> 4;

  if (tid < 64){
    int gn = n0 + tid;
    float r1v = 0.f, r2v = 0.f, one = 0.f;
    if (gn < NN){ r1v = r1[gn]; r2v = r2[gn]; one = 1.f; }
    cS[0][tid] = one;
    cS[1][tid] = r1v;
    cS[2][tid] = fmaf(0.85f, r1v, 1.5e-6f*one);
    cS[3][tid] = r2v;
  }

  f32x4 master[2][2] = {};
  int curt = -1;
  for (int plin = 0; plin < 17; ++plin){
    int t  = (plin == 0) ? 0 : (((plin-1) >> 2) + 1);
    int jj = (plin == 0) ? 0 : ((plin-1) & 3);
    int p  = (plin == 0) ? 0 : (plin + 3);
    if (t != curt){
      __syncthreads();
      const unsigned short* Th = Tsh[t];
      const unsigned short* Tl = Tsl[t];
      #pragma unroll
      for (int l = 0; l < 2; ++l){
        int li = tid + l*256;
        int n = li >> 3, f8 = (li & 7)*8;
        int gn = n0 + n;
        uint4 hv = make_uint4(0,0,0,0), lv = make_uint4(0,0,0,0);
        if (gn < NN){
          hv = *(const uint4*)(Th + (size_t)gn*64 + f8);
          lv = *(const uint4*)(Tl + (size_t)gn*64 + f8);
        }
        *(uint4*)(Ah + n*72 + f8) = hv;
        *(uint4*)(Al + n*72 + f8) = lv;
      }
      curt = t;
    }
    __syncthreads();
    #pragma unroll
    for (int l = 0; l < 2; ++l){
      int li = tid + l*256;
      int c = li >> 3, k8 = (li & 7)*8;
      uint4 hv = *(const uint4*)(Beh + (size_t)p*4096 + c*64 + k8);
      uint4 lv = *(const uint4*)(Bel + (size_t)p*4096 + c*64 + k8);
      *(uint4*)(Bh + c*72 + k8) = hv;
      *(uint4*)(Bl + c*72 + k8) = lv;
    }
    __syncthreads();

    float cvv[2][4];
    #pragma unroll
    for (int rg = 0; rg < 2; ++rg)
      #pragma unroll
      for (int r = 0; r < 4; ++r)
        cvv[rg][r] = cS[jj][rowb + rg*16 + l4*4 + r];

    f32x4 part[2][2] = {};
    #pragma unroll
    for (int s = 0; s < 2; ++s){
      int kc = s*32 + l4*8;
      short8 a0h = *(const short8*)(Ah + (rowb      + l15)*72 + kc);
      short8 a1h = *(const short8*)(Ah + (rowb + 16 + l15)*72 + kc);
      short8 a0l = *(const short8*)(Al + (rowb      + l15)*72 + kc);
      short8 a1l = *(const short8*)(Al + (rowb + 16 + l15)*72 + kc);
      #pragma unroll
      for (int cg = 0; cg < 2; ++cg){
        short8 bh = *(const short8*)(Bh + (colb + cg*16 + l15)*72 + kc);
        short8 bl = *(const short8*)(Bl + (colb + cg*16 + l15)*72 + kc);
        part[0][cg] = __builtin_amdgcn_mfma_f32_16x16x32_bf16(a0h, bh, part[0][cg], 0, 0, 0);
        part[0][cg] = __builtin_amdgcn_mfma_f32_16x16x32_bf16(a0h, bl, part[0][cg], 0, 0, 0);
        part[0][cg] = __builtin_amdgcn_mfma_f32_16x16x32_bf16(a0l, bh, part[0][cg], 0, 0, 0);
        part[1][cg] = __builtin_amdgcn_mfma_f32_16x16x32_bf16(a1h, bh, part[1][cg], 0, 0, 0);
        part[1][cg] = __builtin_amdgcn_mfma_f32_16x16x32_bf16(a1h, bl, part[1][cg], 0, 0, 0);
        part[1][cg] = __builtin_amdgcn_mfma_f32_16x16x32_bf16(a1l, bh, part[1][cg], 0, 0, 0);
      }
    }
    #pragma unroll
    for (int rg = 0; rg < 2; ++rg)
      #pragma unroll
      for (int cg = 0; cg < 2; ++cg)
        #pragma unroll
        for (int r = 0; r < 4; ++r)
          master[rg][cg][r] = fmaf(cvv[rg][r], part[rg][cg][r], master[rg][cg][r]);
  }

  // write Y
  #pragma unroll
  for (int rg = 0; rg < 2; ++rg)
    #pragma unroll
    for (int cg = 0; cg < 2; ++cg)
      #pragma unroll
      for (int r = 0; r < 4; ++r){
        int n = rowb + rg*16 + l4*4 + r;
        int c = colb + cg*16 + l15;
        int gn = n0 + n;
        if (gn < NN && c < KK) Y[(size_t)gn*KK + c] = master[rg][cg][r];
      }

  // restage to As2[n][c] for gram + Qj emission
  __syncthreads();
  #pragma unroll
  for (int rg = 0; rg < 2; ++rg)
    #pragma unroll
    for (int cg = 0; cg < 2; ++cg)
      #pragma unroll
      for (int r = 0; r < 4; ++r){
        int n = rowb + rg*16 + l4*4 + r;
        int c = colb + cg*16 + l15;
        As2[n*68 + c] = master[rg][cg][r];
      }
  __syncthreads();
  // fused block-gram
  {
    int tx = tid & 15, ty = tid >> 4;
    float g[4][4] = {};
    #pragma unroll 4
    for (int n = 0; n < 64; ++n){
      float4 a = *(const float4*)(As2 + n*68 + tx*4);
      float4 b = *(const float4*)(As2 + n*68 + ty*4);
      fma44(a, b, g);
    }
    float* slab = Cpart + (size_t)(blockIdx.x & (GSL-1))*3600;
    #pragma unroll
    for (int i = 0; i < 4; ++i){
      int r = tx*4 + i;
      #pragma unroll
      for (int j = 0; j < 4; ++j){
        int c = ty*4 + j;
        if (r < KK && c < KK) atomicAdd(&slab[r*KK + c], g[i][j]);
      }
    }
  }
  // fused Qj emission: Qj[jk][n] = hi/lo of (c_j ∘ Y)^T, j in {0,1,3}
  for (int o = tid; o < 3*64*64; o += 256){
    int nl = o & 63;
    int jk = o >> 6;
    int gn = n0 + nl;
    if (gn >= NN) continue;
    int j = jk >> 6, k = jk & 63;
    float v = (k < KK) ? As2[nl*68 + k] : 0.f;
    float c = (j == 0) ? 1.f : ((j == 1) ? cS[1][nl] : cS[3][nl]);
    float sv = c * v;
    unsigned short h = f2bf(sv);
    Qjh[(size_t)jk*NN + gn] = h;
    Qjl[(size_t)jk*NN + gn] = f2bf(sv - bf2f(h));
  }
}

// ---------------- backward (unified): per-t-block TT bulk copy OR scatter; XOR-swizzled A tile ----
// T[n][f] stored at Ah[f*PN + (n&7) + 8*((n>>3)^((f>>3)&3))] — both paths identical layout.
__global__ __launch_bounds__(256) void k_bwd(
    const unsigned short* __restrict__ xh, const unsigned short* __restrict__ xl,
    const unsigned short* __restrict__ axh, const unsigned short* __restrict__ axl,
    const unsigned short* __restrict__ s0h, const unsigned short* __restrict__ s0l,
    const unsigned short* __restrict__ s1h, const unsigned short* __restrict__ s1l,
    const unsigned short* __restrict__ s3h, const unsigned short* __restrict__ s3l,
    const unsigned short* __restrict__ TTh, const unsigned short* __restrict__ TTl,
    int tstart,
    const unsigned short* __restrict__ Qjh, const unsigned short* __restrict__ Qjl,
    float* __restrict__ Ppart){
  int tb = blockIdx.x;
  const unsigned short* Th = (tb==0)?xh:(tb==1)?axh:(tb==2)?s0h:(tb==3)?s1h:s3h;
  const unsigned short* Tl = (tb==0)?xl:(tb==1)?axl:(tb==2)?s0l:(tb==3)?s1l:s3l;
  const bool useT = (tb >= tstart);
  const int rel = tb - tstart;
  const int TT2 = (NN + 31)/32;
  int per = (TT2 + BSPLIT - 1)/BSPLIT;
  int t0 = blockIdx.y * per;
  int t1 = t0 + per; if (t1 > TT2) t1 = TT2;

  __shared__ __align__(16) unsigned short Ah[64*PN];
  __shared__ __align__(16) unsigned short Al[64*PN];
  __shared__ __align__(16) unsigned short Bh3[3*64*PN];
  __shared__ __align__(16) unsigned short Bl3[3*64*PN];

  int tid = threadIdx.x;
  int lane = tid & 63, wid = tid >> 6;
  int rowb = (wid & 1)*32, colb = (wid >> 1)*32;
  int l15 = lane & 15, l4 = lane >> 4;

  // precomputed swizzled read offsets (row-dependent block permutation)
  int r0 = rowb + l15;
  int r1r = rowb + 16 + l15;
  int off0 = r0*PN  + (aswz(r0,  l4) << 3);
  int off1 = r1r*PN + (aswz(r1r, l4) << 3);

  f32x4 master[3][2][2] = {};

  for (int tl = t0; tl < t1; ++tl){
    int nb = tl*32;
    __syncthreads();
    if (useT){
      // bulk copy from pre-transposed TT; write to swizzled block
      int f = tid >> 2, ch = (tid & 3)*8;
      uint4 hv = *(const uint4*)(TTh + (size_t)(rel*64+f)*NN + nb + ch);
      uint4 lv = *(const uint4*)(TTl + (size_t)(rel*64+f)*NN + nb + ch);
      int col = aswz(f, ch >> 3) << 3;
      *(uint4*)(Ah + f*PN + col) = hv;
      *(uint4*)(Al + f*PN + col) = lv;
    } else {
      // scatter path: in-LDS transpose from row-major; swizzled column
      int n = tid >> 3, f8 = (tid & 7)*8;
      int gn = nb + n;
      uint4 hv = make_uint4(0,0,0,0), lv = make_uint4(0,0,0,0);
      if (gn < NN){
        hv = *(const uint4*)(Th + (size_t)gn*64 + f8);
        lv = *(const uint4*)(Tl + (size_t)gn*64 + f8);
      }
      const unsigned short* hp = (const unsigned short*)&hv;
      const unsigned short* lp = (const unsigned short*)&lv;
      int nlo = n & 7, nblk = n >> 3;
      #pragma unroll
      for (int i = 0; i < 8; ++i){
        int f = f8 + i;
        int col = nlo | (aswz(f, nblk) << 3);
        Ah[f*PN + col] = hp[i];
        Al[f*PN + col] = lp[i];
      }
    }
    #pragma unroll
    for (int u = 0; u < 3; ++u){
      int l = tid + u*256;
      int row = l >> 2, ch = (l & 3)*8;
      uint4 hv = *(const uint4*)(Qjh + (size_t)row*NN + nb + ch);
      uint4 lv = *(const uint4*)(Qjl + (size_t)row*NN + nb + ch);
      *(uint4*)(Bh3 + row*PN + ch) = hv;
      *(uint4*)(Bl3 + row*PN + ch) = lv;
    }
    __syncthreads();
    short8 a0h = *(const short8*)(Ah + off0);
    short8 a1h = *(const short8*)(Ah + off1);
    short8 a0l = *(const short8*)(Al + off0);
    short8 a1l = *(const short8*)(Al + off1);
    #pragma unroll
    for (int jj = 0; jj < 3; ++jj){
      #pragma unroll
      for (int cg = 0; cg < 2; ++cg){
        short8 bh = *(const short8*)(Bh3 + jj*64*PN + (colb + cg*16 + l15)*PN + l4*8);
        short8 bl = *(const short8*)(Bl3 + jj*64*PN + (colb + cg*16 + l15)*PN + l4*8);
        master[jj][0][cg] = __builtin_amdgcn_mfma_f32_16x16x32_bf16(a0h, bh, master[jj][0][cg], 0, 0, 0);
        master[jj][0][cg] = __builtin_amdgcn_mfma_f32_16x16x32_bf16(a0h, bl, master[jj][0][cg], 0, 0, 0);
        master[jj][0][cg] = __builtin_amdgcn_mfma_f32_16x16x32_bf16(a0l, bh, master[jj][0][cg], 0, 0, 0);
        master[jj][1][cg] = __builtin_amdgcn_mfma_f32_16x16x32_bf16(a1h, bh, master[jj][1][cg], 0, 0, 0);
        master[jj][1][cg] = __builtin_amdgcn_mfma_f32_16x16x32_bf16(a1h, bl, master[jj][1][cg], 0, 0, 0);
        master[jj][1][cg] = __builtin_amdgcn_mfma_f32_16x16x32_bf16(a1l, bh, master[jj][1][cg], 0, 0, 0);
      }
    }
  }

  float* dst = Ppart + (size_t)blockIdx.y * 76800;
  #pragma unroll
  for (int jj = 0; jj < 3; ++jj){
    int j = (jj == 2) ? 3 : jj;
    #pragma unroll
    for (int rg = 0; rg < 2; ++rg)
      #pragma unroll
      for (int cg = 0; cg < 2; ++cg)
        #pragma unroll
        for (int r = 0; r < 4; ++r){
          int f = rowb + rg*16 + l4*4 + r;
          int kcol = colb + cg*16 + l15;
          if (kcol < KK)
            dst[(size_t)((blockIdx.x*4 + j)*64 + f)*60 + kcol] = master[jj][rg][cg][r];
        }
  }
}

// Z[F x 60] from Ppart (BSPLIT private slabs); j=2 synthesized
__global__ void k_zasm(const float* __restrict__ Ppart, float* __restrict__ Z){
  int gid = blockIdx.x*blockDim.x + threadIdx.x;
  if (gid >= FF*KK) return;
  int f = gid / 60, k = gid - (gid/60)*60;
  int b = f >> 6, fi = f & 63;
  auto raw = [&](int t, int j)->float{
    size_t e = (size_t)((t*4 + j)*64 + fi)*60 + k;
    float s = 0.f;
    for (int bb = 0; bb < BSPLIT; ++bb) s += Ppart[(size_t)bb*76800 + e];
    return s;
  };
  auto fetch = [&](int t, int j)->float{
    if (j == 2) return 0.85f*raw(t,1) + 1.5e-6f*raw(t,0);
    return raw(t,j);
  };
  float val;
  if (b == 0)      val = raw(0,0);
  else if (b < 5)  val = fetch(1, b-1);
  else if (b < 9)  val = fetch(2, b-5);
  else if (b < 13) val = fetch(3, b-9);
  else if (b < 17) val = 0.85f*fetch(3, b-13) + 1.5e-6f*fetch(2, b-13);
  else             val = fetch(4, b-17);
  Z[gid] = val;
}

// ---------------- CholQR pieces ----------------
__global__ __launch_bounds__(256) void k_syrkp(const float* __restrict__ X, int nrows,
                                               float* __restrict__ Cpart){
  const int TTs = (nrows + 15)/16;
  int per = (TTs + gridDim.x - 1)/gridDim.x;
  int t0 = blockIdx.x*per;
  int t1 = t0 + per; if (t1 > TTs) t1 = TTs;
  __shared__ float Xs[16][64];
  int tid = threadIdx.x;
  int tx = tid & 15, ty = tid >> 4;
  float acc[4][4] = {};
  for (int tl = t0; tl < t1; ++tl){
    int nbase = tl*16;
    if (tid < 240){
      int n = tid / 15, ci = tid - (tid/15)*15;
      float4 v = make_float4(0.f,0.f,0.f,0.f);
      int gn = nbase + n;
      if (gn < nrows) v = *(const float4*)(X + (size_t)gn*KK + ci*4);
      *(float4*)&Xs[n][ci*4] = v;
    } else {
      int n = tid - 240;
      Xs[n][60]=0.f; Xs[n][61]=0.f; Xs[n][62]=0.f; Xs[n][63]=0.f;
    }
    __syncthreads();
    #pragma unroll
    for (int n = 0; n < 16; ++n){
      float4 a = *(const float4*)&Xs[n][tx*4];
      float4 b = *(const float4*)&Xs[n][ty*4];
      fma44(a, b, acc);
    }
    __syncthreads();
  }
  float* dst = Cpart + (size_t)blockIdx.x*3600;
  #pragma unroll
  for (int i = 0; i < 4; ++i){
    int r = tx*4 + i;
    #pragma unroll
    for (int j = 0; j < 4; ++j){
      int c = ty*4 + j;
      if (r < KK && c < KK) dst[r*KK + c] = acc[i][j];
    }
  }
}

__global__ void k_cred(const float* __restrict__ Cpart, int nparts, float* __restrict__ Cm){
  int gid = blockIdx.x*blockDim.x + threadIdx.x;
  if (gid >= 3600) return;
  float s = 0.f;
  for (int b = 0; b < nparts; ++b) s += Cpart[(size_t)b*3600 + gid];
  Cm[gid] = s;
}

__global__ __launch_bounds__(256) void k_cholinv(const float* __restrict__ Cin,
                                                 float* __restrict__ Rinv){
  __shared__ float R[60][65];
  __shared__ float Ri[60][65];
  __shared__ float Tmp[30][33];
  __shared__ float ridge;
  int t = threadIdx.x;
  for (int i = t; i < 3840; i += 256){
    int r = i >> 6, c = i & 63;
    if (c < 60) R[r][c] = Cin[r*60 + c];
  }
  __syncthreads();
  if (t == 0){
    float tr = 0.f;
    for (int i = 0; i < 60; ++i) tr += R[i][i];
    ridge = 1e-7f*(tr/60.f) + 1e-30f;
  }
  __syncthreads();
  if (t < 60) R[t][t] += ridge;
  __syncthreads();
  for (int j = 0; j < 60; ++j){
    float d  = fmaxf(R[j][j], 1e-30f);
    float dp = (j > 0) ? fmaxf(R[j-1][j-1], 1e-30f) : 1.f;
    float inv = 1.0f / d;
    float rsp = (j > 0) ? (1.0f / sqrtf(dp)) : 1.f;
    int nrow = 59 - j;
    for (int task = t; task < (nrow+1)*64; task += 256){
      int rr = task >> 6, i2 = task & 63;
      if (rr < nrow){
        int k = j + 1 + rr;
        if (i2 >= k && i2 < 60) R[k][i2] -= R[j][k]*R[j][i2]*inv;
      } else {
        if (j > 0 && i2 >= j-1 && i2 < 60) R[j-1][i2] *= rsp;
      }
    }
    __syncthreads();
  }
  if (t == 0) R[59][59] = sqrtf(fmaxf(R[59][59], 1e-30f));
  __syncthreads();
  for (int i = t; i < 3840; i += 256){ int r = i >> 6, c = i & 63; Ri[r][c] = 0.f; }
  __syncthreads();
  if (t < 60){
    int c = t;
    int lo = (c < 30) ? 0 : 30;
    Ri[c][c] = 1.0f / R[c][c];
    for (int i = c-1; i >= lo; --i){
      float s = 0.f;
      for (int k = i+1; k <= c; ++k) s += R[i][k]*Ri[k][c];
      Ri[i][c] = -s / R[i][i];
    }
  }
  __syncthreads();
  for (int idx2 = t; idx2 < 960; idx2 += 256){
    int r = idx2 >> 5, c = idx2 & 31;
    if (c < 30){
      float s = 0.f;
      for (int k = 0; k <= c; ++k) s += R[r][30+k]*Ri[30+k][30+c];
      Tmp[r][c] = s;
    }
  }
  __syncthreads();
  for (int idx2 = t; idx2 < 960; idx2 += 256){
    int r = idx2 >> 5, c = idx2 & 31;
    if (c < 30){
      float s = 0.f;
      for (int k = r; k < 30; ++k) s += Ri[r][k]*Tmp[k][c];
      Ri[r][30+c] = -s;
    }
  }
  __syncthreads();
  for (int i = t; i < 3600; i += 256) Rinv[i] = Ri[i/60][i%60];
}

__global__ __launch_bounds__(256) void k_cholinv2(const float* __restrict__ Gin,
                                                  float* __restrict__ Rinv){
  __shared__ float G[60][65];
  __shared__ float RN[60][65];
  __shared__ float T1[60][65];
  __shared__ float G2[60][65];
  __shared__ float Tmp[30][33];
  __shared__ float ridge;
  int t = threadIdx.x;
  for (int i = t; i < 3840; i += 256){
    int r = i >> 6, c = i & 63;
    if (c < 60){ G[r][c] = Gin[r*60 + c]; RN[r][c] = Rinv[r*60 + c]; }
  }
  __syncthreads();
  for (int o = t; o < 3600; o += 256){
    int i = o/60, j = o - (o/60)*60;
    float s = 0.f;
    for (int k = 0; k <= j; ++k) s = fmaf(G[i][k], RN[k][j], s);
    T1[i][j] = s;
  }
  __syncthreads();
  for (int o = t; o < 3600; o += 256){
    int i = o/60, j = o - (o/60)*60;
    float s = 0.f;
    for (int k = 0; k <= i; ++k) s = fmaf(RN[k][i], T1[k][j], s);
    G2[i][j] = s;
  }
  __syncthreads();
  if (t == 0){
    float tr = 0.f;
    for (int i = 0; i < 60; ++i) tr += G2[i][i];
    ridge = 1e-7f*(tr/60.f) + 1e-30f;
  }
  __syncthreads();
  if (t < 60) G2[t][t] += ridge;
  __syncthreads();
  for (int j = 0; j < 60; ++j){
    float d  = fmaxf(G2[j][j], 1e-30f);
    float dp = (j > 0) ? fmaxf(G2[j-1][j-1], 1e-30f) : 1.f;
    float inv = 1.0f / d;
    float rsp = (j > 0) ? (1.0f / sqrtf(dp)) : 1.f;
    int nrow = 59 - j;
    for (int task = t; task < (nrow+1)*64; task += 256){
      int rr = task >> 6, i2 = task & 63;
      if (rr < nrow){
        int k = j + 1 + rr;
        if (i2 >= k && i2 < 60) G2[k][i2] -= G2[j][k]*G2[j][i2]*inv;
      } else {
        if (j > 0 && i2 >= j-1 && i2 < 60) G2[j-1][i2] *= rsp;
      }
    }
    __syncthreads();
  }
  if (t == 0) G2[59][59] = sqrtf(fmaxf(G2[59][59], 1e-30f));
  __syncthreads();
  for (int i = t; i < 3840; i += 256){ int r = i >> 6, c = i & 63; T1[r][c] = 0.f; }
  __syncthreads();
  if (t < 60){
    int c = t;
    int lo = (c < 30) ? 0 : 30;
    T1[c][c] = 1.0f / G2[c][c];
    for (int i = c-1; i >= lo; --i){
      float s = 0.f;
      for (int k = i+1; k <= c; ++k) s += G2[i][k]*T1[k][c];
      T1[i][c] = -s / G2[i][i];
    }
  }
  __syncthreads();
  for (int idx2 = t; idx2 < 960; idx2 += 256){
    int r = idx2 >> 5, c = idx2 & 31;
    if (c < 30){
      float s = 0.f;
      for (int k = 0; k <= c; ++k) s += G2[r][30+k]*T1[30+k][30+c];
      Tmp[r][c] = s;
    }
  }
  __syncthreads();
  for (int idx2 = t; idx2 < 960; idx2 += 256){
    int r = idx2 >> 5, c = idx2 & 31;
    if (c < 30){
      float s = 0.f;
      for (int k = r; k < 30; ++k) s += T1[r][k]*Tmp[k][c];
      T1[r][30+c] = -s;
    }
  }
  __syncthreads();
  for (int o = t; o < 3600; o += 256){
    int i = o/60, j = o - (o/60)*60;
    float s = 0.f;
    if (i <= j){
      for (int k = i; k <= j; ++k) s = fmaf(RN[i][k], T1[k][j], s);
    }
    Rinv[o] = s;
  }
}

__global__ __launch_bounds__(256) void k_applyR(const float* Yin,
    const float* __restrict__ Rinv, float* Xout, int nrows){
  __shared__ float Rs[3600];
  for (int i = threadIdx.x; i < 3600; i += 256) Rs[i] = Rinv[i];
  __syncthreads();
  int w = threadIdx.x >> 6, lane = threadIdx.x & 63;
  #pragma unroll
  for (int r = 0; r < 4; ++r){
    int n = blockIdx.x*16 + w*4 + r;
    if (n >= nrows) continue;
    const float* y = Yin + (size_t)n*KK;
    float accv = 0.f;
    #pragma unroll 10
    for (int k2 = 0; k2 < KK; ++k2) accv = fmaf(y[k2], Rs[k2*KK + lane], accv);
    if (lane < KK) Xout[(size_t)n*KK + lane] = accv;
  }
}

__global__ void k_wb(const float* __restrict__ Z, const float* __restrict__ w,
                     float* __restrict__ WB){
  int gid = blockIdx.x*blockDim.x + threadIdx.x;
  if (gid >= KK*64) return;
  int r = gid >> 6, d = gid & 63;
  float acc = 0.f;
  for (int f = 0; f < FF; ++f) acc = fmaf(Z[(size_t)f*KK + r], w[(size_t)f*64 + d], acc);
  WB[gid] = acc;
}

// Jacobi eigensolver — two-pass, 3 sweeps (VERIFIED r10-r18; 2 sweeps failed r15)
__global__ __launch_bounds__(512) void k_jacobi(const float* __restrict__ Min,
                                                float* __restrict__ U50){
  __shared__ float A[60][65];
  __shared__ float Vv[60][65];
  __shared__ float cs[32], sn[32];
  __shared__ int pp[32], qq[32];
  __shared__ float ev[64];
  __shared__ int idx[64];
  int t = threadIdx.x;
  for (int i = t; i < 3840; i += 512){
    int r = i >> 6, c = i & 63;
    if (c < 60){ A[r][c] = Min[r*60 + c]; Vv[r][c] = (r == c) ? 1.f : 0.f; }
  }
  __syncthreads();
  for (int sweep = 0; sweep < 3; ++sweep){
    for (int round = 0; round < 59; ++round){
      if (t < 30){
        int i = t, j2 = 59 - t;
        int p = (i == 0) ? 0 : ((i - 1 + round) % 59 + 1);
        int q = ((j2 - 1 + round) % 59 + 1);
        if (p > q){ int tv = p; p = q; q = tv; }
        pp[t] = p; qq[t] = q;
        float app = A[p][p], aqq = A[q][q], apq = A[p][q];
        float c, s;
        if (fabsf(apq) < 1e-36f){ c = 1.f; s = 0.f; }
        else {
          float tau = (aqq - app) / (2.f * apq);
          float tt = ((tau >= 0.f) ? 1.f : -1.f) / (fabsf(tau) + sqrtf(1.f + tau*tau));
          c = 1.f / sqrtf(1.f + tt*tt);
          s = tt * c;
        }
        cs[t] = c; sn[t] = s;
      }
      __syncthreads();
      for (int task = t; task < 1920; task += 512){
        int k = task >> 6, i = task & 63;
        if (i < 60){
          int p = pp[k], q = qq[k];
          float c = cs[k], s = sn[k];
          float aip = A[i][p], aiq = A[i][q];
          A[i][p] = c*aip - s*aiq;  A[i][q] = s*aip + c*aiq;
          float vip = Vv[i][p], viq = Vv[i][q];
          Vv[i][p] = c*vip - s*viq; Vv[i][q] = s*vip + c*viq;
        }
      }
      __syncthreads();
      for (int task = t; task < 1920; task += 512){
        int k = task >> 6, i = task & 63;
        if (i < 60){
          int p = pp[k], q = qq[k];
          float c = cs[k], s = sn[k];
          float api = A[p][i], aqi = A[q][i];
          A[p][i] = c*api - s*aqi;  A[q][i] = s*api + c*aqi;
        }
      }
      __syncthreads();
    }
  }
  if (t < 60) ev[t] = A[t][t];
  __syncthreads();
  if (t < 60){
    float mine = ev[t];
    int rank = 0;
    for (int j = 0; j < 60; ++j){
      float o = ev[j];
      if (o > mine || (o == mine && j < t)) ++rank;
    }
    if (rank < RK) idx[rank] = t;
  }
  __syncthreads();
  for (int i2 = t; i2 < 60*RK; i2 += 512){
    int r = i2 / RK, c = i2 - (i2/RK)*RK;
    U50[i2] = Vv[r][idx[c]];
  }
}

// fused projector chain + Rinv fold: TW1 = Rinv · (U50 U50^T WB W1)
__global__ __launch_bounds__(256) void k_chain(const float* __restrict__ U50,
    const float* __restrict__ WB, const float* __restrict__ W1,
    const float* __restrict__ Rinv, float* __restrict__ TW1){
  __shared__ float Us[60][52];
  __shared__ float WBs[60][64];
  __shared__ float G[50][64];
  __shared__ float Ts[60][64];
  __shared__ float Tm2[60][33];
  int t = threadIdx.x;
  for (int i = t; i < 60*RK; i += 256) Us[i/RK][i%RK] = U50[i];
  for (int i = t; i < 3840; i += 256) WBs[i>>6][i&63] = WB[i];
  __syncthreads();
  for (int o = t; o < RK*64; o += 256){
    int r = o >> 6, d = o & 63;
    float acc = 0.f;
    #pragma unroll 10
    for (int i = 0; i < KK; ++i) acc = fmaf(Us[i][r], WBs[i][d], acc);
    G[r][d] = acc;
  }
  __syncthreads();
  for (int o = t; o < KK*64; o += 256){
    int i = o >> 6, d = o & 63;
    float acc = 0.f;
    #pragma unroll 10
    for (int r = 0; r < RK; ++r) acc = fmaf(Us[i][r], G[r][d], acc);
    Ts[i][d] = acc;
  }
  __syncthreads();
  for (int o = t; o < KK*HIDN; o += 256){
    int i = o >> 5, j = o & 31;
    float acc = 0.f;
    #pragma unroll 8
    for (int d = 0; d < 64; ++d) acc = fmaf(Ts[i][d], W1[d*HIDN + j], acc);
    Tm2[i][j] = acc;
  }
  __syncthreads();
  for (int o = t; o < KK*HIDN; o += 256){
    int i = o >> 5, j = o & 31;
    float acc = 0.f;
    for (int k = i; k < KK; ++k) acc = fmaf(Rinv[i*KK + k], Tm2[k][j], acc);
    TW1[o] = acc;
  }
}

__global__ __launch_bounds__(256) void k_hid(const float* __restrict__ Q,
    const float* __restrict__ TW1, const float* __restrict__ b1, float* __restrict__ hid){
  __shared__ float Ts[KK*HIDN];
  __shared__ float bs[HIDN];
  for (int i = threadIdx.x; i < KK*HIDN; i += 256) Ts[i] = TW1[i];
  if (threadIdx.x < HIDN) bs[threadIdx.x] = b1[threadIdx.x];
  __syncthreads();
  int gid = blockIdx.x*256 + threadIdx.x;
  if (gid >= NN*HIDN) return;
  int n = gid >> 5, j = gid & 31;
  const float* q = Q + (size_t)n*KK;
  float a = bs[j];
  #pragma unroll 10
  for (int k2 = 0; k2 < KK; ++k2) a = fmaf(q[k2], Ts[k2*HIDN + j], a);
  hid[gid] = (a >= 0.f) ? a : 0.01f*a;
}

__global__ void k_gstart(const int* __restrict__ gids, int* __restrict__ gst){
  int g = blockIdx.x*blockDim.x + threadIdx.x;
  if (g > GG) return;
  if (g == GG){ gst[GG] = NN; return; }
  int lo = 0, hi = NN;
  while (lo < hi){ int mid = (lo + hi) >> 1; if (gids[mid] < g) lo = mid + 1; else hi = mid; }
  gst[g] = lo;
}

__global__ __launch_bounds__(256) void k_gpool(const float* __restrict__ hid,
    const int* __restrict__ gst, float* __restrict__ pooled){
  int g = blockIdx.x;
  __shared__ float part[8][32];
  int w = threadIdx.x >> 5, lane = threadIdx.x & 31;
  int s = gst[g], e = gst[g+1];
  float acc = 0.f;
  for (int n = s + w; n < e; n += 8)
    acc += hid[(size_t)n*HIDN + lane];
  part[w][lane] = acc;
  __syncthreads();
  if (w == 0){
    float v = 0.f;
    #pragma unroll
    for (int i = 0; i < 8; ++i) v += part[i][lane];
    pooled[g*HIDN + lane] = v;
  }
}

__global__ void k_out(const float* __restrict__ pooled, const float* __restrict__ W2,
                      float* __restrict__ out){
  int gid = blockIdx.x*blockDim.x + threadIdx.x;
  if (gid >= GG*NCL) return;
  int g = gid / NCL, c = gid - (gid/NCL)*NCL;
  const float* p = pooled + g*HIDN;
  float acc = 0.f;
  #pragma unroll
  for (int k = 0; k < HIDN; ++k) acc = fmaf(p[k], W2[(size_t)k*NCL + c], acc);
  out[gid] = acc;
}

// ---------------- host ----------------
extern "C" void kernel_launch(void* const* d_in, const int* in_sizes, int n_in,
                              void* d_out, int out_size, void* d_ws, size_t ws_size,
                              hipStream_t stream){
  (void)in_sizes; (void)n_in; (void)out_size;
  const float* x   = (const float*)d_in[0];
  const int*  rows = (const int*)d_in[1];
  const int*  cols = (const int*)d_in[2];
  const int*  gids = (const int*)d_in[3];
  const float* wM  = (const float*)d_in[5];
  const float* W1  = (const float*)d_in[6];
  const float* b1  = (const float*)d_in[7];
  const float* W2  = (const float*)d_in[8];
  float* out = (float*)d_out;

  char* base = (char*)d_ws;
  size_t off = 0;
  auto alloc = [&](size_t bytes)->char*{
    off = (off + 255) & ~(size_t)255;
    char* p = base + off; off += bytes; return p;
  };
  float* ax    = (float*)alloc((size_t)NN*64*4);        // dead after hop2
  int*   csr   = (int*)  alloc((size_t)EE*4);           // adjacent; dead after hop2
  unsigned short* Qjh = (unsigned short*)ax;            // 38.4MB overlay of ax+csr
  unsigned short* xh  = (unsigned short*)alloc((size_t)NN*64*2);
  unsigned short* xl  = (unsigned short*)alloc((size_t)NN*64*2);
  unsigned short* axh = (unsigned short*)alloc((size_t)NN*64*2);
  unsigned short* axl = (unsigned short*)alloc((size_t)NN*64*2);
  unsigned short* s0h = (unsigned short*)alloc((size_t)NN*64*2);
  unsigned short* s0l = (unsigned short*)alloc((size_t)NN*64*2);
  unsigned short* s1h = (unsigned short*)alloc((size_t)NN*64*2);
  unsigned short* s1l = (unsigned short*)alloc((size_t)NN*64*2);
  unsigned short* s3h = (unsigned short*)alloc((size_t)NN*64*2);
  unsigned short* s3l = (unsigned short*)alloc((size_t)NN*64*2);
  float* Y     = (float*)alloc((size_t)NN*KK*4);
  unsigned short* Qjl = (unsigned short*)alloc((size_t)3*64*NN*2);  // reused as hid later
  float* Ppart = (float*)alloc((size_t)BSPLIT*76800*4);
  unsigned short* Beh = (unsigned short*)alloc((size_t)20*4096*2);
  unsigned short* Bel = (unsigned short*)alloc((size_t)20*4096*2);
  float* Om    = (float*)alloc((size_t)FF*KK*4);
  float* Zf    = (float*)alloc((size_t)FF*KK*4);
  float* Cm    = (float*)alloc(3600*4);
  float* Rinv  = (float*)alloc(3600*4);
  float* Mm    = (float*)alloc(3600*4);
  float* U50   = (float*)alloc(60*RK*4);
  float* WB    = (float*)alloc(KK*64*4);
  float* TW1   = (float*)alloc(KK*HIDN*4);
  float* pooled= (float*)alloc((size_t)GG*HIDN*4);
  float* r1    = (float*)alloc((size_t)NN*4);
  float* r2    = (float*)alloc((size_t)NN*4);
  int* cnt     = (int*)alloc((size_t)NN*4);
  int* rowptr  = (int*)alloc((size_t)(NN+1)*4);
  int* tmpc    = (int*)alloc((size_t)NN*4);
  int* gst     = (int*)alloc((size_t)(GG+1)*4);
  int* bsums   = (int*)alloc(256*4);
  float* hid   = (float*)Qjl;
  float* Cpart = Ppart;
  size_t off_base = off;
  if (off_base > ws_size) return;

  // ---- granular TT: fit as many transposed tensors as the ws holds ----
  const size_t perT = (size_t)64*NN*2;   // 12.8 MB per tensor per (hi|lo)
  int nTT = 0;
  if (ws_size > off_base + 1024){
    size_t avail = ws_size - off_base - 1024;
    nTT = (int)(avail / (2*perT));
    if (nTT > 5) nTT = 5;
  }
  unsigned short* TTh = nullptr;
  unsigned short* TTl = nullptr;
  if (nTT > 0){
    TTh = (unsigned short*)alloc(perT * (size_t)nTT);
    TTl = (unsigned short*)alloc(perT * (size_t)nTT);
    if (off > ws_size){ nTT = 0; TTh = nullptr; TTl = nullptr; }
  }
  int tstart = 5 - nTT;

  const int SCAN_B = (NN + 1023) / 1024;

  // ---- graph prep ----
  hipMemsetAsync(cnt, 0, (size_t)NN*4, stream);
  k_count<<<(EE+255)/256, 256, 0, stream>>>(rows, cnt);
  k_scan1<<<SCAN_B, 1024, 0, stream>>>(cnt, rowptr, bsums);
  k_scan2<<<1, 64, 0, stream>>>(bsums, SCAN_B);
  k_scan3<<<(NN+255)/256, 256, 0, stream>>>(cnt, bsums, rowptr);
  hipMemsetAsync(tmpc, 0, (size_t)NN*4, stream);
  k_scatter<<<(EE+255)/256, 256, 0, stream>>>(rows, cols, rowptr, tmpc, csr);
  k_degr<<<(NN+255)/256, 256, 0, stream>>>(cnt, r1, r2);

  // ---- base tensors (+ hi/lo); ax/csr dead after hop2 ----
  k_xcvt<<<(NN*64+255)/256, 256, 0, stream>>>(x, xh, xl);
  k_hop1<<<(NN+3)/4, 256, 0, stream>>>(x, rowptr, csr, ax, axh, axl);
  k_hop2<<<(NN+3)/4, 256, 0, stream>>>(rowptr, csr, ax, r1, r2, s0h, s0l, s1h, s1l, s3h, s3l);
  if (nTT > 0)
    k_tcvt<<<dim3((NN+63)/64, nTT), 256, 0, stream>>>(xh, xl, axh, axl, s0h, s0l,
                                                      s1h, s1l, s3h, s3l, tstart, TTh, TTl);

  // ---- omega ----
  k_omega<<<(FF*KK+255)/256, 256, 0, stream>>>(Om);

  auto fwdg = [&](){    // fwd + fused gram + fused Qj emission
    hipMemsetAsync(Cpart, 0, (size_t)GSL*3600*4, stream);
    k_fwd<<<(NN+63)/64, 256, 0, stream>>>(xh, xl, axh, axl, s0h, s0l, s1h, s1l, s3h, s3l,
                                          Beh, Bel, r1, r2, Y, Cpart, Qjh, Qjl);
  };
  auto bwd = [&](){     // uses Qj emitted by the preceding fwdg (Y unchanged in between)
    k_bwd<<<dim3(5, BSPLIT), 256, 0, stream>>>(xh, xl, axh, axl, s0h, s0l, s1h, s1l,
                                               s3h, s3l, TTh, TTl, tstart, Qjh, Qjl, Ppart);
    k_zasm<<<(FF*KK+255)/256, 256, 0, stream>>>(Ppart, Zf);
  };

  // ---- Y0 = h @ omega (+gram +Qj) ----
  k_beff<<<(20*4096+255)/256, 256, 0, stream>>>(Om, Beh, Bel);
  fwdg();

  // ---- power iterations ----
  for (int it = 0; it < 4; ++it){
    k_cred<<<15, 256, 0, stream>>>(Cpart, GSL, Cm);
    k_cholinv<<<1, 256, 0, stream>>>(Cm, Rinv);                  // RinvN
    bwd();                                                       // Zraw = h^T Y
    k_syrkp<<<84, 256, 0, stream>>>(Zf, FF, Cpart);
    k_cred<<<15, 256, 0, stream>>>(Cpart, 84, Cm);
    k_cholinv2<<<1, 256, 0, stream>>>(Cm, Rinv);                 // Rinv := Rtot
    k_beffT<<<20, 256, 0, stream>>>(Zf, Rinv, Beh, Bel);
    fwdg();                                                      // Y = h Qf (+gram +Qj)
  }

  // ---- final: RinvN; Zf = (h^T Y)·RinvN ----
  k_cred<<<15, 256, 0, stream>>>(Cpart, GSL, Cm);
  k_cholinv<<<1, 256, 0, stream>>>(Cm, Rinv);
  bwd();                                                         // Zraw = h^T Y
  k_applyR<<<(FF+15)/16, 256, 0, stream>>>(Zf, Rinv, Zf, FF);    // Zf = Zraw·RinvN
  k_syrkp<<<84, 256, 0, stream>>>(Zf, FF, Cpart);
  k_cred<<<15, 256, 0, stream>>>(Cpart, 84, Mm);
  k_wb<<<(KK*64+255)/256, 256, 0, stream>>>(Zf, wM, WB);

  // ---- eigensolve + projector chain (Rinv folded into TW1) ----
  k_jacobi<<<1, 512, 0, stream>>>(Mm, U50);
  k_chain<<<1, 256, 0, stream>>>(U50, WB, W1, Rinv, TW1);

  // ---- MLP + pooling (hid overlays Qjl) ----
  k_hid<<<(NN*HIDN+255)/256, 256, 0, stream>>>(Y, TW1, b1, hid);
  k_gstart<<<1, 256, 0, stream>>>(gids, gst);
  k_gpool<<<GG, 256, 0, stream>>>(hid, gst, pooled);
  k_out<<<(GG*NCL+255)/256, 256, 0, stream>>>(pooled, W2, out);
}